// Round 1
// baseline (4622.302 us; speedup 1.0000x reference)
//
#include <hip/hip_runtime.h>
#include <hip/hip_bf16.h>
#include <math.h>

namespace {
constexpr int B = 16, L0 = 512, L1 = 256, NS = 32, D = 256, H = 8, NL = 4, HM = 4;
constexpr int T = L0 + L1 + NS + 1;   // 801
constexpr int HD = D / H;             // 32
constexpr int NTOK = B * T;           // 12816
constexpr int NS_S = L0 + L1;         // 768
constexpr int NS_E = NS_S + NS;       // 800
constexpr float EPS = 1e-5f;
constexpr float SCALE = 0.17677669529663687f;  // 32^-0.5
}

// ---------------- build x = concat(seq0+dom0, seq1+dom1, ns, cls) ----------------
__global__ __launch_bounds__(256) void k_build_x(
    const float* __restrict__ s0, const float* __restrict__ s1,
    const float* __restrict__ ns, const float* __restrict__ dom,
    const float* __restrict__ cls, float* __restrict__ x)
{
    const int row = blockIdx.x;          // 0..NTOK-1
    const int b = row / T, t = row % T;
    const int d = threadIdx.x;           // 0..255
    float v;
    if (t < L0)        v = s0[((size_t)b * L0 + t) * D + d] + dom[d];
    else if (t < NS_S) v = s1[((size_t)b * L1 + (t - L0)) * D + d] + dom[D + d];
    else if (t < NS_E) v = ns[((size_t)b * NS + (t - NS_S)) * D + d];
    else               v = cls[d];
    x[(size_t)row * D + d] = v;
}

// ---------------- LayerNorm over D=256, one wave per row ----------------
__global__ __launch_bounds__(256) void k_ln(
    const float* __restrict__ x, const float* __restrict__ w,
    const float* __restrict__ bsh, float* __restrict__ y, int nrows)
{
    const int wid = threadIdx.x >> 6, lane = threadIdx.x & 63;
    const int row = blockIdx.x * 4 + wid;
    if (row >= nrows) return;
    float4 v = *(const float4*)(x + (size_t)row * D + lane * 4);
    float s  = v.x + v.y + v.z + v.w;
    float ss = v.x * v.x + v.y * v.y + v.z * v.z + v.w * v.w;
#pragma unroll
    for (int o = 32; o; o >>= 1) { s += __shfl_xor(s, o); ss += __shfl_xor(ss, o); }
    const float mean = s * (1.f / D);
    const float var  = ss * (1.f / D) - mean * mean;
    const float r = rsqrtf(var + EPS);
    float4 wv = *(const float4*)(w + lane * 4);
    float4 bv = *(const float4*)(bsh + lane * 4);
    float4 o4;
    o4.x = (v.x - mean) * r * wv.x + bv.x;
    o4.y = (v.y - mean) * r * wv.y + bv.y;
    o4.z = (v.z - mean) * r * wv.z + bv.z;
    o4.w = (v.w - mean) * r * wv.w + bv.w;
    *(float4*)(y + (size_t)row * D + lane * 4) = o4;
}

// ---------------- final LN on CLS row only ----------------
__global__ __launch_bounds__(64) void k_final_ln(
    const float* __restrict__ x, const float* __restrict__ w,
    const float* __restrict__ bsh, float* __restrict__ out)
{
    const int b = blockIdx.x, lane = threadIdx.x;
    const float* xr = x + (size_t)(b * T + (T - 1)) * D;
    float4 v = *(const float4*)(xr + lane * 4);
    float s  = v.x + v.y + v.z + v.w;
    float ss = v.x * v.x + v.y * v.y + v.z * v.z + v.w * v.w;
#pragma unroll
    for (int o = 32; o; o >>= 1) { s += __shfl_xor(s, o); ss += __shfl_xor(ss, o); }
    const float mean = s * (1.f / D);
    const float var  = ss * (1.f / D) - mean * mean;
    const float r = rsqrtf(var + EPS);
    float4 wv = *(const float4*)(w + lane * 4);
    float4 bv = *(const float4*)(bsh + lane * 4);
    float4 o4;
    o4.x = (v.x - mean) * r * wv.x + bv.x;
    o4.y = (v.y - mean) * r * wv.y + bv.y;
    o4.z = (v.z - mean) * r * wv.z + bv.z;
    o4.w = (v.w - mean) * r * wv.w + bv.w;
    *(float4*)(out + (size_t)b * D + lane * 4) = o4;
}

// ---------------- generic fp32 tiled GEMM: C = A[M,K] @ W[K,N] + bias (+gelu)(+res) ----------------
template<bool GELU, bool RES>
__global__ __launch_bounds__(256) void k_gemm(
    const float* __restrict__ A, const float* __restrict__ W,
    const float* __restrict__ bias, float* __restrict__ C,
    const float* __restrict__ res, int Mdim, int Ndim, int Kdim)
{
    __shared__ float As[16][64];  // transposed: As[k][m]
    __shared__ float Ws[16][64];  // Ws[k][n]
    const int tid = threadIdx.x;
    const int tx = tid & 15, ty = tid >> 4;
    const int m0 = blockIdx.x * 64, n0 = blockIdx.y * 64;
    const int lr = tid >> 2, lc4 = tid & 3;     // A-tile loader: row, float4 col
    const int wr = tid >> 4, wc4 = tid & 15;    // W-tile loader
    float acc[4][4] = {};

    for (int k0 = 0; k0 < Kdim; k0 += 16) {
        int arow = m0 + lr; if (arow >= Mdim) arow = Mdim - 1;   // clamp (edge tile)
        float4 a4 = *(const float4*)(A + (size_t)arow * Kdim + k0 + lc4 * 4);
        float4 w4 = *(const float4*)(W + (size_t)(k0 + wr) * Ndim + n0 + wc4 * 4);
        __syncthreads();
        As[lc4 * 4 + 0][lr] = a4.x;
        As[lc4 * 4 + 1][lr] = a4.y;
        As[lc4 * 4 + 2][lr] = a4.z;
        As[lc4 * 4 + 3][lr] = a4.w;
        *(float4*)&Ws[wr][wc4 * 4] = w4;
        __syncthreads();
#pragma unroll
        for (int kk = 0; kk < 16; ++kk) {
            float4 wv = *(const float4*)&Ws[kk][tx * 4];
            float a0 = As[kk][ty * 4 + 0];
            float a1 = As[kk][ty * 4 + 1];
            float a2 = As[kk][ty * 4 + 2];
            float a3 = As[kk][ty * 4 + 3];
            acc[0][0] += a0 * wv.x; acc[0][1] += a0 * wv.y; acc[0][2] += a0 * wv.z; acc[0][3] += a0 * wv.w;
            acc[1][0] += a1 * wv.x; acc[1][1] += a1 * wv.y; acc[1][2] += a1 * wv.z; acc[1][3] += a1 * wv.w;
            acc[2][0] += a2 * wv.x; acc[2][1] += a2 * wv.y; acc[2][2] += a2 * wv.z; acc[2][3] += a2 * wv.w;
            acc[3][0] += a3 * wv.x; acc[3][1] += a3 * wv.y; acc[3][2] += a3 * wv.z; acc[3][3] += a3 * wv.w;
        }
    }
#pragma unroll
    for (int i = 0; i < 4; ++i) {
        int m = m0 + ty * 4 + i;
        if (m >= Mdim) break;
#pragma unroll
        for (int j = 0; j < 4; ++j) {
            int n = n0 + tx * 4 + j;
            float v = acc[i][j] + bias[n];
            if (GELU) v = 0.5f * v * (1.0f + erff(v * 0.70710678118654752f));
            if (RES)  v += res[(size_t)m * Ndim + n];
            C[(size_t)m * Ndim + n] = v;
        }
    }
}

// ---------------- attention: one wave per (b,h,q); mask computed on the fly ----------------
__global__ __launch_bounds__(256) void k_attn(
    const float* __restrict__ qkv, const int* __restrict__ len0,
    const int* __restrict__ len1, float* __restrict__ out)
{
    __shared__ float probs[4][T];    // 4 * 801 * 4B
    __shared__ float qs[4][HD];
    const int wid = threadIdx.x >> 6, lane = threadIdx.x & 63;
    const int b = blockIdx.x >> 3, h = blockIdx.x & 7;
    const int q = blockIdx.y * 4 + wid;
    if (q >= T) return;
    const int l0b = len0[b], l1b = len1[b];

    const float* qp = qkv + ((size_t)(b * T + q) * 3) * D + h * HD;
    if (lane < HD) qs[wid][lane] = qp[lane];

    float sv[13];
    float mx = -1e30f;
#pragma unroll
    for (int i = 0; i < 13; ++i) {
        const int k = lane + i * 64;
        float s = -1e30f;
        if (k < T) {
            bool valid = (k < L0) ? (k < l0b) : (k < NS_S) ? ((k - L0) < l1b) : true;
            bool m;
            if (q < L0)        m = (k <= q) || (k >= NS_S && k < NS_E);
            else if (q < NS_S) m = (k >= L0 && k <= q) || (k >= NS_S && k < NS_E);
            else if (q < NS_E) m = (k < NS_E);
            else               m = (k < NS_E) || (k == T - 1);
            if (m && valid) {
                const float* kp = qkv + ((size_t)(b * T + k) * 3 + 1) * D + h * HD;
                float acc = 0.f;
#pragma unroll
                for (int d = 0; d < HD; d += 4) {
                    float4 k4 = *(const float4*)(kp + d);
                    acc += k4.x * qs[wid][d] + k4.y * qs[wid][d + 1]
                         + k4.z * qs[wid][d + 2] + k4.w * qs[wid][d + 3];
                }
                s = acc * SCALE;
                mx = fmaxf(mx, s);
            }
        }
        sv[i] = s;
    }
#pragma unroll
    for (int o = 32; o; o >>= 1) mx = fmaxf(mx, __shfl_xor(mx, o));

    float sum = 0.f;
#pragma unroll
    for (int i = 0; i < 13; ++i) {
        const int k = lane + i * 64;
        if (k < T) {
            float e = (sv[i] > -1e29f) ? expf(sv[i] - mx) : 0.f;
            probs[wid][k] = e;
            sum += e;
        }
    }
#pragma unroll
    for (int o = 32; o; o >>= 1) sum += __shfl_xor(sum, o);
    const float inv = 1.f / fmaxf(sum, 1e-30f);

    // PV: lanes 0..31 own d, lanes 32..63 the second half of k
    const int d = lane & 31, half = lane >> 5;
    const float* vp = qkv + ((size_t)(b * T) * 3 + 2) * D + h * HD + d;
    float acc = 0.f;
    for (int k = half; k < T; k += 2)
        acc += probs[wid][k] * vp[(size_t)k * (3 * D)];
    acc += __shfl_xor(acc, 32);
    if (lane < 32) out[(size_t)(b * T + q) * D + h * HD + d] = acc * inv;
}

extern "C" void kernel_launch(void* const* d_in, const int* in_sizes, int n_in,
                              void* d_out, int out_size, void* d_ws, size_t ws_size,
                              hipStream_t stream)
{
    const float* seq0 = (const float*)d_in[0];
    const float* seq1 = (const float*)d_in[1];
    const int*   len0 = (const int*)d_in[2];
    const int*   len1 = (const int*)d_in[3];
    const float* nst  = (const float*)d_in[4];
    const float* dom  = (const float*)d_in[5];
    const float* cls  = (const float*)d_in[6];
    const float* ln1w = (const float*)d_in[7];
    const float* ln1b = (const float*)d_in[8];
    const float* qkvw = (const float*)d_in[9];
    const float* qkvb = (const float*)d_in[10];
    const float* outw = (const float*)d_in[11];
    const float* outb = (const float*)d_in[12];
    const float* ln2w = (const float*)d_in[13];
    const float* ln2b = (const float*)d_in[14];
    const float* f1w  = (const float*)d_in[15];
    const float* f1b  = (const float*)d_in[16];
    const float* f2w  = (const float*)d_in[17];
    const float* f2b  = (const float*)d_in[18];
    const float* flnw = (const float*)d_in[19];
    const float* flnb = (const float*)d_in[20];

    float* x   = (float*)d_ws;                 // NTOK*D
    float* xn  = x + (size_t)NTOK * D;         // NTOK*D
    float* big = xn + (size_t)NTOK * D;        // NTOK*HM*D (holds qkv OR ffn hidden)

    k_build_x<<<NTOK, 256, 0, stream>>>(seq0, seq1, nst, dom, cls, x);

    const int lnGrid = (NTOK + 3) / 4;
    const int gm = (NTOK + 63) / 64;           // 201

    for (int l = 0; l < NL; ++l) {
        k_ln<<<lnGrid, 256, 0, stream>>>(x, ln1w + l * D, ln1b + l * D, xn, NTOK);
        k_gemm<false, false><<<dim3(gm, (3 * D) / 64), 256, 0, stream>>>(
            xn, qkvw + (size_t)l * D * 3 * D, qkvb + (size_t)l * 3 * D, big, nullptr,
            NTOK, 3 * D, D);
        k_attn<<<dim3(B * H, (T + 3) / 4), 256, 0, stream>>>(big, len0, len1, xn);
        k_gemm<false, true><<<dim3(gm, D / 64), 256, 0, stream>>>(
            xn, outw + (size_t)l * D * D, outb + (size_t)l * D, x, x,
            NTOK, D, D);
        k_ln<<<lnGrid, 256, 0, stream>>>(x, ln2w + l * D, ln2b + l * D, xn, NTOK);
        k_gemm<true, false><<<dim3(gm, (HM * D) / 64), 256, 0, stream>>>(
            xn, f1w + (size_t)l * D * HM * D, f1b + (size_t)l * HM * D, big, nullptr,
            NTOK, HM * D, D);
        k_gemm<false, true><<<dim3(gm, D / 64), 256, 0, stream>>>(
            big, f2w + (size_t)l * HM * D * D, f2b + (size_t)l * D, x, x,
            NTOK, D, HM * D);
    }
    k_final_ln<<<B, 64, 0, stream>>>(x, flnw, flnb, (float*)d_out);
}

// Round 2
// 1555.451 us; speedup vs baseline: 2.9717x; 2.9717x over previous
//
#include <hip/hip_runtime.h>
#include <hip/hip_bf16.h>
#include <math.h>

typedef __attribute__((ext_vector_type(8))) unsigned short ushort8;
typedef __attribute__((ext_vector_type(8))) short short8;
typedef __attribute__((ext_vector_type(4))) float f32x4;

namespace {
constexpr int B = 16, L0 = 512, L1 = 256, NS = 32, D = 256, H = 8, NL = 4, HM = 4;
constexpr int T = L0 + L1 + NS + 1;   // 801
constexpr int HD = D / H;             // 32
constexpr int NTOK = B * T;           // 12816
constexpr int NS_S = L0 + L1;         // 768
constexpr int NS_E = NS_S + NS;       // 800
constexpr int TPAD = 832;             // 13*64, tile-padded T
constexpr float EPS = 1e-5f;
constexpr float SCALE = 0.17677669529663687f;  // 32^-0.5
}

__device__ __forceinline__ ushort f2bf(float f) {
    union { float f; unsigned u; } v; v.f = f;
    return (ushort)((v.u + 0x7fffu + ((v.u >> 16) & 1u)) >> 16);
}

// ---------------- build x = concat(seq0+dom0, seq1+dom1, ns, cls) ----------------
__global__ __launch_bounds__(256) void k_build_x(
    const float* __restrict__ s0, const float* __restrict__ s1,
    const float* __restrict__ ns, const float* __restrict__ dom,
    const float* __restrict__ cls, float* __restrict__ x)
{
    const int row = blockIdx.x;
    const int b = row / T, t = row % T;
    const int d = threadIdx.x;
    float v;
    if (t < L0)        v = s0[((size_t)b * L0 + t) * D + d] + dom[d];
    else if (t < NS_S) v = s1[((size_t)b * L1 + (t - L0)) * D + d] + dom[D + d];
    else if (t < NS_E) v = ns[((size_t)b * NS + (t - NS_S)) * D + d];
    else               v = cls[d];
    x[(size_t)row * D + d] = v;
}

// ---------------- LayerNorm over D=256, one wave per row ----------------
__global__ __launch_bounds__(256) void k_ln(
    const float* __restrict__ x, const float* __restrict__ w,
    const float* __restrict__ bsh, float* __restrict__ y, int nrows)
{
    const int wid = threadIdx.x >> 6, lane = threadIdx.x & 63;
    const int row = blockIdx.x * 4 + wid;
    if (row >= nrows) return;
    float4 v = *(const float4*)(x + (size_t)row * D + lane * 4);
    float s  = v.x + v.y + v.z + v.w;
    float ss = v.x * v.x + v.y * v.y + v.z * v.z + v.w * v.w;
#pragma unroll
    for (int o = 32; o; o >>= 1) { s += __shfl_xor(s, o); ss += __shfl_xor(ss, o); }
    const float mean = s * (1.f / D);
    const float var  = ss * (1.f / D) - mean * mean;
    const float r = rsqrtf(var + EPS);
    float4 wv = *(const float4*)(w + lane * 4);
    float4 bv = *(const float4*)(bsh + lane * 4);
    float4 o4;
    o4.x = (v.x - mean) * r * wv.x + bv.x;
    o4.y = (v.y - mean) * r * wv.y + bv.y;
    o4.z = (v.z - mean) * r * wv.z + bv.z;
    o4.w = (v.w - mean) * r * wv.w + bv.w;
    *(float4*)(y + (size_t)row * D + lane * 4) = o4;
}

// ---------------- final LN on CLS row only ----------------
__global__ __launch_bounds__(64) void k_final_ln(
    const float* __restrict__ x, const float* __restrict__ w,
    const float* __restrict__ bsh, float* __restrict__ out)
{
    const int b = blockIdx.x, lane = threadIdx.x;
    const float* xr = x + (size_t)(b * T + (T - 1)) * D;
    float4 v = *(const float4*)(xr + lane * 4);
    float s  = v.x + v.y + v.z + v.w;
    float ss = v.x * v.x + v.y * v.y + v.z * v.z + v.w * v.w;
#pragma unroll
    for (int o = 32; o; o >>= 1) { s += __shfl_xor(s, o); ss += __shfl_xor(ss, o); }
    const float mean = s * (1.f / D);
    const float var  = ss * (1.f / D) - mean * mean;
    const float r = rsqrtf(var + EPS);
    float4 wv = *(const float4*)(w + lane * 4);
    float4 bv = *(const float4*)(bsh + lane * 4);
    float4 o4;
    o4.x = (v.x - mean) * r * wv.x + bv.x;
    o4.y = (v.y - mean) * r * wv.y + bv.y;
    o4.z = (v.z - mean) * r * wv.z + bv.z;
    o4.w = (v.w - mean) * r * wv.w + bv.w;
    *(float4*)(out + (size_t)b * D + lane * 4) = o4;
}

// ---------------- generic fp32 tiled GEMM: C = A[M,K] @ W[K,N] + bias (+gelu)(+res) ----------------
template<bool GELU, bool RES>
__global__ __launch_bounds__(256) void k_gemm(
    const float* __restrict__ A, const float* __restrict__ W,
    const float* __restrict__ bias, float* __restrict__ C,
    const float* __restrict__ res, int Mdim, int Ndim, int Kdim)
{
    __shared__ float As[16][64];
    __shared__ float Ws[16][64];
    const int tid = threadIdx.x;
    const int tx = tid & 15, ty = tid >> 4;
    const int m0 = blockIdx.x * 64, n0 = blockIdx.y * 64;
    const int lr = tid >> 2, lc4 = tid & 3;
    const int wr = tid >> 4, wc4 = tid & 15;
    float acc[4][4] = {};

    for (int k0 = 0; k0 < Kdim; k0 += 16) {
        int arow = m0 + lr; if (arow >= Mdim) arow = Mdim - 1;
        float4 a4 = *(const float4*)(A + (size_t)arow * Kdim + k0 + lc4 * 4);
        float4 w4 = *(const float4*)(W + (size_t)(k0 + wr) * Ndim + n0 + wc4 * 4);
        __syncthreads();
        As[lc4 * 4 + 0][lr] = a4.x;
        As[lc4 * 4 + 1][lr] = a4.y;
        As[lc4 * 4 + 2][lr] = a4.z;
        As[lc4 * 4 + 3][lr] = a4.w;
        *(float4*)&Ws[wr][wc4 * 4] = w4;
        __syncthreads();
#pragma unroll
        for (int kk = 0; kk < 16; ++kk) {
            float4 wv = *(const float4*)&Ws[kk][tx * 4];
            float a0 = As[kk][ty * 4 + 0];
            float a1 = As[kk][ty * 4 + 1];
            float a2 = As[kk][ty * 4 + 2];
            float a3 = As[kk][ty * 4 + 3];
            acc[0][0] += a0 * wv.x; acc[0][1] += a0 * wv.y; acc[0][2] += a0 * wv.z; acc[0][3] += a0 * wv.w;
            acc[1][0] += a1 * wv.x; acc[1][1] += a1 * wv.y; acc[1][2] += a1 * wv.z; acc[1][3] += a1 * wv.w;
            acc[2][0] += a2 * wv.x; acc[2][1] += a2 * wv.y; acc[2][2] += a2 * wv.z; acc[2][3] += a2 * wv.w;
            acc[3][0] += a3 * wv.x; acc[3][1] += a3 * wv.y; acc[3][2] += a3 * wv.z; acc[3][3] += a3 * wv.w;
        }
    }
#pragma unroll
    for (int i = 0; i < 4; ++i) {
        int m = m0 + ty * 4 + i;
        if (m >= Mdim) break;
#pragma unroll
        for (int j = 0; j < 4; ++j) {
            int n = n0 + tx * 4 + j;
            float v = acc[i][j] + bias[n];
            if (GELU) v = 0.5f * v * (1.0f + erff(v * 0.70710678118654752f));
            if (RES)  v += res[(size_t)m * Ndim + n];
            C[(size_t)m * Ndim + n] = v;
        }
    }
}

// ---------------- repack K,V of one layer's qkv to bf16: Kb[bh][832][32], Vt[bh][32][832] ----------------
__global__ __launch_bounds__(256) void k_repack(
    const float* __restrict__ qkv, ushort* __restrict__ Kb, ushort* __restrict__ Vt)
{
    const int bh = blockIdx.x, tt = blockIdx.y;
    const int b = bh >> 3, h = bh & 7;
    const int tid = threadIdx.x;
    const int r = tid >> 2, c = tid & 3;
    const int t = tt * 64 + r;
    __shared__ ushort vtile[64][40];
    ushort8 k8 = {0,0,0,0,0,0,0,0}, v8 = {0,0,0,0,0,0,0,0};
    if (t < T) {
        const float* kp = qkv + ((size_t)(b * T + t) * 3 + 1) * D + h * HD + c * 8;
        const float* vp = kp + D;
#pragma unroll
        for (int j = 0; j < 8; ++j) { k8[j] = f2bf(kp[j]); v8[j] = f2bf(vp[j]); }
    }
    *(ushort8*)(Kb + ((size_t)bh * TPAD + tt * 64 + r) * HD + c * 8) = k8;
    *(ushort8*)&vtile[r][c * 8] = v8;
    __syncthreads();
    const int d = tid >> 3, cc = tid & 7;
    ushort8 o;
#pragma unroll
    for (int j = 0; j < 8; ++j) o[j] = vtile[cc * 8 + j][d];
    *(ushort8*)(Vt + ((size_t)bh * HD + d) * TPAD + tt * 64 + cc * 8) = o;
}

// ---------------- flash attention: block = (q-tile 64, bh); 4 waves x 16 q-rows ----------------
__global__ __launch_bounds__(256) void k_flash(
    const float* __restrict__ qkv, const ushort* __restrict__ Kb,
    const ushort* __restrict__ Vt, const int* __restrict__ len0,
    const int* __restrict__ len1, float* __restrict__ out)
{
    const int qt = blockIdx.x;       // 0..12
    const int bh = blockIdx.y;       // 0..127
    const int b = bh >> 3, h = bh & 7;
    const int tid = threadIdx.x, lane = tid & 63, w = tid >> 6;
    const int lo = lane & 15, g = lane >> 4;
    const int q0 = qt * 64 + w * 16;
    const int l0b = len0[b], l1b = len1[b];

    __shared__ ushort Ks[64][40];      // K rows (80B stride: 2-way banks)
    __shared__ ushort Vs[32][72];      // V^T rows (144B stride)
    __shared__ ushort Ps[4][16][72];   // per-wave P tile

    // Q A-frag: lane holds Q[q0+lo][g*8 .. g*8+7] (fp32 -> bf16 on the fly)
    int qrow = q0 + lo; if (qrow > T - 1) qrow = T - 1;
    const float* qp = qkv + ((size_t)(b * T + qrow) * 3) * D + h * HD + g * 8;
    short8 qf;
#pragma unroll
    for (int j = 0; j < 8; ++j) qf[j] = (short)f2bf(qp[j]);

    f32x4 o0 = {0.f, 0.f, 0.f, 0.f}, o1 = {0.f, 0.f, 0.f, 0.f};
    float mrow[4] = {-1e30f, -1e30f, -1e30f, -1e30f};
    float srow[4] = {0.f, 0.f, 0.f, 0.f};

    const int kts = (qt >= 8 && qt < 12) ? 8 : 0;   // q>=512 rows never see k<512
    const int ntiles = (qt - kts + 1) + (qt < 12 ? 1 : 0);

    for (int it = 0; it < ntiles; ++it) {
        int kt = kts + it; if (kt > qt) kt = 12;    // ns/cls tile last
        const int k0 = kt * 64;

        __syncthreads();
        {   // stage K tile (64x32 bf16) and V^T tile (32x64 bf16)
            const int r = tid >> 2, c = tid & 3;
            *(ushort8*)&Ks[r][c * 8] =
                *(const ushort8*)(Kb + ((size_t)bh * TPAD + k0 + r) * HD + c * 8);
            const int dd = tid >> 3, cc = tid & 7;
            *(ushort8*)&Vs[dd][cc * 8] =
                *(const ushort8*)(Vt + ((size_t)bh * HD + dd) * TPAD + k0 + cc * 8);
        }
        __syncthreads();

        // S = Q K^T  (4 n-subtiles of 16 cols)
        f32x4 s[4];
#pragma unroll
        for (int n = 0; n < 4; ++n) {
            short8 kf = *(const short8*)&Ks[n * 16 + lo][g * 8];
            f32x4 z = {0.f, 0.f, 0.f, 0.f};
            s[n] = __builtin_amdgcn_mfma_f32_16x16x32_bf16(qf, kf, z, 0, 0, 0);
        }

        // mask + online softmax. D-layout: row=g*4+i, col=n*16+lo
        float p[4][4];
        float tm[4] = {-1e30f, -1e30f, -1e30f, -1e30f};
#pragma unroll
        for (int n = 0; n < 4; ++n) {
            const int k = k0 + n * 16 + lo;
            const bool kval = (k < L0) ? (k < l0b) : (k < NS_S) ? ((k - L0) < l1b) : true;
#pragma unroll
            for (int i = 0; i < 4; ++i) {
                const int q = q0 + g * 4 + i;
                bool m = (q < L0)   ? ((k <= q) || (k >= NS_S && k < NS_E))
                       : (q < NS_S) ? ((k >= L0 && k <= q) || (k >= NS_S && k < NS_E))
                       : (q < NS_E) ? (k < NS_E)
                                    : ((k < NS_E) || (k == T - 1));
                const float sv = (m && kval) ? s[n][i] * SCALE : -1e30f;
                p[n][i] = sv;
                tm[i] = fmaxf(tm[i], sv);
            }
        }
#pragma unroll
        for (int i = 0; i < 4; ++i) {
            float t0 = tm[i];
            t0 = fmaxf(t0, __shfl_xor(t0, 1));
            t0 = fmaxf(t0, __shfl_xor(t0, 2));
            t0 = fmaxf(t0, __shfl_xor(t0, 4));
            t0 = fmaxf(t0, __shfl_xor(t0, 8));
            const float mnew = fmaxf(mrow[i], t0);
            const float scl = __expf(mrow[i] - mnew);
            mrow[i] = mnew;
            srow[i] *= scl;
            o0[i] *= scl; o1[i] *= scl;
            float rs = 0.f;
#pragma unroll
            for (int n = 0; n < 4; ++n) {
                const float e = (p[n][i] > -1e29f) ? __expf(p[n][i] - mnew) : 0.f;
                p[n][i] = e;
                rs += e;
            }
            srow[i] += rs;
        }

        // P -> LDS (bf16), then PV MFMAs
#pragma unroll
        for (int n = 0; n < 4; ++n)
#pragma unroll
            for (int i = 0; i < 4; ++i)
                Ps[w][g * 4 + i][n * 16 + lo] = f2bf(p[n][i]);
        __syncthreads();
#pragma unroll
        for (int kk = 0; kk < 2; ++kk) {
            short8 pf = *(const short8*)&Ps[w][lo][kk * 32 + g * 8];
            short8 v0 = *(const short8*)&Vs[lo][kk * 32 + g * 8];
            short8 v1 = *(const short8*)&Vs[16 + lo][kk * 32 + g * 8];
            o0 = __builtin_amdgcn_mfma_f32_16x16x32_bf16(pf, v0, o0, 0, 0, 0);
            o1 = __builtin_amdgcn_mfma_f32_16x16x32_bf16(pf, v1, o1, 0, 0, 0);
        }
    }

    // normalize + store
#pragma unroll
    for (int i = 0; i < 4; ++i) {
        float ssum = srow[i];
        ssum += __shfl_xor(ssum, 1);
        ssum += __shfl_xor(ssum, 2);
        ssum += __shfl_xor(ssum, 4);
        ssum += __shfl_xor(ssum, 8);
        const float inv = 1.f / fmaxf(ssum, 1e-30f);
        const int q = q0 + g * 4 + i;
        if (q < T) {
            float* orow = out + (size_t)(b * T + q) * D + h * HD;
            orow[lo]      = o0[i] * inv;
            orow[16 + lo] = o1[i] * inv;
        }
    }
}

extern "C" void kernel_launch(void* const* d_in, const int* in_sizes, int n_in,
                              void* d_out, int out_size, void* d_ws, size_t ws_size,
                              hipStream_t stream)
{
    const float* seq0 = (const float*)d_in[0];
    const float* seq1 = (const float*)d_in[1];
    const int*   len0 = (const int*)d_in[2];
    const int*   len1 = (const int*)d_in[3];
    const float* nst  = (const float*)d_in[4];
    const float* dom  = (const float*)d_in[5];
    const float* cls  = (const float*)d_in[6];
    const float* ln1w = (const float*)d_in[7];
    const float* ln1b = (const float*)d_in[8];
    const float* qkvw = (const float*)d_in[9];
    const float* qkvb = (const float*)d_in[10];
    const float* outw = (const float*)d_in[11];
    const float* outb = (const float*)d_in[12];
    const float* ln2w = (const float*)d_in[13];
    const float* ln2b = (const float*)d_in[14];
    const float* f1w  = (const float*)d_in[15];
    const float* f1b  = (const float*)d_in[16];
    const float* f2w  = (const float*)d_in[17];
    const float* f2b  = (const float*)d_in[18];
    const float* flnw = (const float*)d_in[19];
    const float* flnb = (const float*)d_in[20];

    float* x   = (float*)d_ws;                 // NTOK*D
    float* xn  = x + (size_t)NTOK * D;         // NTOK*D
    float* big = xn + (size_t)NTOK * D;        // NTOK*HM*D (qkv or ffn hidden)
    ushort* Kb = (ushort*)(big + (size_t)NTOK * HM * D);   // 128*832*32 bf16
    ushort* Vt = Kb + (size_t)B * H * TPAD * HD;           // 128*32*832 bf16

    k_build_x<<<NTOK, 256, 0, stream>>>(seq0, seq1, nst, dom, cls, x);

    const int lnGrid = (NTOK + 3) / 4;
    const int gm = (NTOK + 63) / 64;

    for (int l = 0; l < NL; ++l) {
        k_ln<<<lnGrid, 256, 0, stream>>>(x, ln1w + l * D, ln1b + l * D, xn, NTOK);
        k_gemm<false, false><<<dim3(gm, (3 * D) / 64), 256, 0, stream>>>(
            xn, qkvw + (size_t)l * D * 3 * D, qkvb + (size_t)l * 3 * D, big, nullptr,
            NTOK, 3 * D, D);
        k_repack<<<dim3(B * H, TPAD / 64), 256, 0, stream>>>(big, Kb, Vt);
        k_flash<<<dim3(TPAD / 64, B * H), 256, 0, stream>>>(big, Kb, Vt, len0, len1, xn);
        k_gemm<false, true><<<dim3(gm, D / 64), 256, 0, stream>>>(
            xn, outw + (size_t)l * D * D, outb + (size_t)l * D, x, x,
            NTOK, D, D);
        k_ln<<<lnGrid, 256, 0, stream>>>(x, ln2w + l * D, ln2b + l * D, xn, NTOK);
        k_gemm<true, false><<<dim3(gm, (HM * D) / 64), 256, 0, stream>>>(
            xn, f1w + (size_t)l * D * HM * D, f1b + (size_t)l * HM * D, big, nullptr,
            NTOK, HM * D, D);
        k_gemm<false, true><<<dim3(gm, D / 64), 256, 0, stream>>>(
            big, f2w + (size_t)l * HM * D * D, f2b + (size_t)l * D, x, x,
            NTOK, D, HM * D);
    }
    k_final_ln<<<B, 64, 0, stream>>>(x, flnw, flnb, (float*)d_out);
}

// Round 3
// 667.196 us; speedup vs baseline: 6.9280x; 2.3313x over previous
//
#include <hip/hip_runtime.h>
#include <hip/hip_bf16.h>
#include <math.h>

typedef __attribute__((ext_vector_type(8))) unsigned short ushort8;
typedef __attribute__((ext_vector_type(8))) short short8;
typedef __attribute__((ext_vector_type(4))) float f32x4;
typedef __attribute__((ext_vector_type(4))) unsigned short ushort4v;
typedef unsigned int u32;

namespace {
constexpr int B = 16, L0 = 512, L1 = 256, NS = 32, D = 256, H = 8, NL = 4, HM = 4;
constexpr int T = L0 + L1 + NS + 1;   // 801
constexpr int HD = D / H;             // 32
constexpr int NTOK = B * T;           // 12816
constexpr int NS_S = L0 + L1;         // 768
constexpr int NS_E = NS_S + NS;       // 800
constexpr int TPAD = 832;             // 13*64
constexpr float EPS = 1e-5f;
constexpr float SCALE = 0.17677669529663687f;  // 32^-0.5
}

__device__ __forceinline__ ushort f2bf(float f) {
    union { float f; unsigned u; } v; v.f = f;
    return (ushort)((v.u + 0x7fffu + ((v.u >> 16) & 1u)) >> 16);
}

__device__ __forceinline__ void gload_lds16(const void* g, void* l) {
    __builtin_amdgcn_global_load_lds(
        (const __attribute__((address_space(1))) u32*)g,
        (__attribute__((address_space(3))) u32*)l, 16, 0, 0);
}

// ---------------- build x ----------------
__global__ __launch_bounds__(256) void k_build_x(
    const float* __restrict__ s0, const float* __restrict__ s1,
    const float* __restrict__ ns, const float* __restrict__ dom,
    const float* __restrict__ cls, float* __restrict__ x)
{
    const int row = blockIdx.x;
    const int b = row / T, t = row % T;
    const int d = threadIdx.x;
    float v;
    if (t < L0)        v = s0[((size_t)b * L0 + t) * D + d] + dom[d];
    else if (t < NS_S) v = s1[((size_t)b * L1 + (t - L0)) * D + d] + dom[D + d];
    else if (t < NS_E) v = ns[((size_t)b * NS + (t - NS_S)) * D + d];
    else               v = cls[d];
    x[(size_t)row * D + d] = v;
}

// ---------------- weight prep: W[K][N] f32 -> W^T[N][K] bf16, per-layer via blockIdx.z ----------------
__global__ __launch_bounds__(256) void k_wprep(
    const float* __restrict__ src, ushort* __restrict__ dst, int K, int N)
{
    const size_t off = (size_t)blockIdx.z * K * N;
    src += off; dst += off;
    __shared__ float t[32][33];
    const int kb = blockIdx.x * 32, nb = blockIdx.y * 32;
    const int c = threadIdx.x & 31, r8 = threadIdx.x >> 5;
#pragma unroll
    for (int rr = 0; rr < 32; rr += 8)
        t[r8 + rr][c] = src[(size_t)(kb + r8 + rr) * N + nb + c];
    __syncthreads();
#pragma unroll
    for (int rr = 0; rr < 32; rr += 8)
        dst[(size_t)(nb + r8 + rr) * K + kb + c] = f2bf(t[c][r8 + rr]);
}

// ---------------- LayerNorm: fp32 in -> bf16 out ----------------
__global__ __launch_bounds__(256) void k_ln(
    const float* __restrict__ x, const float* __restrict__ w,
    const float* __restrict__ bsh, ushort* __restrict__ y, int nrows)
{
    const int wid = threadIdx.x >> 6, lane = threadIdx.x & 63;
    const int row = blockIdx.x * 4 + wid;
    if (row >= nrows) return;
    float4 v = *(const float4*)(x + (size_t)row * D + lane * 4);
    float s  = v.x + v.y + v.z + v.w;
    float ss = v.x * v.x + v.y * v.y + v.z * v.z + v.w * v.w;
#pragma unroll
    for (int o = 32; o; o >>= 1) { s += __shfl_xor(s, o); ss += __shfl_xor(ss, o); }
    const float mean = s * (1.f / D);
    const float var  = ss * (1.f / D) - mean * mean;
    const float r = rsqrtf(var + EPS);
    float4 wv = *(const float4*)(w + lane * 4);
    float4 bv = *(const float4*)(bsh + lane * 4);
    ushort4v o4;
    o4[0] = f2bf((v.x - mean) * r * wv.x + bv.x);
    o4[1] = f2bf((v.y - mean) * r * wv.y + bv.y);
    o4[2] = f2bf((v.z - mean) * r * wv.z + bv.z);
    o4[3] = f2bf((v.w - mean) * r * wv.w + bv.w);
    *(ushort4v*)(y + (size_t)row * D + lane * 4) = o4;
}

// ---------------- final LN on CLS row (fp32 out) ----------------
__global__ __launch_bounds__(64) void k_final_ln(
    const float* __restrict__ x, const float* __restrict__ w,
    const float* __restrict__ bsh, float* __restrict__ out)
{
    const int b = blockIdx.x, lane = threadIdx.x;
    const float* xr = x + (size_t)(b * T + (T - 1)) * D;
    float4 v = *(const float4*)(xr + lane * 4);
    float s  = v.x + v.y + v.z + v.w;
    float ss = v.x * v.x + v.y * v.y + v.z * v.z + v.w * v.w;
#pragma unroll
    for (int o = 32; o; o >>= 1) { s += __shfl_xor(s, o); ss += __shfl_xor(ss, o); }
    const float mean = s * (1.f / D);
    const float var  = ss * (1.f / D) - mean * mean;
    const float r = rsqrtf(var + EPS);
    float4 wv = *(const float4*)(w + lane * 4);
    float4 bv = *(const float4*)(bsh + lane * 4);
    float4 o4;
    o4.x = (v.x - mean) * r * wv.x + bv.x;
    o4.y = (v.y - mean) * r * wv.y + bv.y;
    o4.z = (v.z - mean) * r * wv.z + bv.z;
    o4.w = (v.w - mean) * r * wv.w + bv.w;
    *(float4*)(out + (size_t)b * D + lane * 4) = o4;
}

// ---------------- bf16 MFMA GEMM: C = A[M,K]bf16 @ Wt[N,K]^T bf16 + bias (+gelu)(+res) ----------------
// 128x128 tile, BK=64, 4 waves (2x2), double-buffered LDS, global_load_lds staging,
// T2 XOR-swizzle: linear LDS dest + inverse-swizzled global source + swizzled ds_read.
template<bool GELU, bool RES, bool OBF>
__global__ __launch_bounds__(256) void k_gemm_mfma(
    const ushort* __restrict__ A, const ushort* __restrict__ Wt,
    const float* __restrict__ bias, void* __restrict__ Cout,
    const float* __restrict__ res, int M, int N, int K)
{
    __shared__ ushort As[2][128 * 64];
    __shared__ ushort Bs[2][128 * 64];
    const int tid = threadIdx.x;
    const int lane = tid & 63, w = tid >> 6;
    const int lo = lane & 15, g = lane >> 4;
    const int wr = w >> 1, wc = w & 1;
    const int m0 = blockIdx.x * 128, n0 = blockIdx.y * 128;

    f32x4 zero = {0.f, 0.f, 0.f, 0.f};
    f32x4 acc[4][4];
#pragma unroll
    for (int mi = 0; mi < 4; ++mi)
#pragma unroll
        for (int ni = 0; ni < 4; ++ni) acc[mi][ni] = zero;

    // staging source pointers (4 chunks of 1KB per wave per tile)
    const ushort* srcA[4];
    const ushort* srcB[4];
    int ldsOff[4];
#pragma unroll
    for (int i = 0; i < 4; ++i) {
        const int idx16 = (w * 4 + i) * 64 + lane;      // 16B unit index 0..1023
        const int row = idx16 >> 3;                     // 0..127
        const int scb = ((idx16 & 7) * 16) ^ ((row & 7) << 4);  // swizzled src byte col
        int arow = m0 + row; if (arow >= M) arow = M - 1;
        srcA[i] = A  + (size_t)arow * K + (scb >> 1);
        srcB[i] = Wt + (size_t)(n0 + row) * K + (scb >> 1);
        ldsOff[i] = (w * 4 + i) * 512;                  // elements
    }

    const int NT = K >> 6;

    // prologue: stage tile 0 into buf 0
#pragma unroll
    for (int i = 0; i < 4; ++i) {
        gload_lds16(srcA[i], &As[0][ldsOff[i]]);
        gload_lds16(srcB[i], &Bs[0][ldsOff[i]]);
    }
    asm volatile("s_waitcnt vmcnt(0)");
    __syncthreads();

    for (int t = 0; t < NT; ++t) {
        const int buf = t & 1;
        if (t + 1 < NT) {
            const int nb = buf ^ 1, ko = (t + 1) * 64;
#pragma unroll
            for (int i = 0; i < 4; ++i) {
                gload_lds16(srcA[i] + ko, &As[nb][ldsOff[i]]);
                gload_lds16(srcB[i] + ko, &Bs[nb][ldsOff[i]]);
            }
        }
#pragma unroll
        for (int kk = 0; kk < 2; ++kk) {
            const int kb = (kk * 64 + g * 16) ^ ((lo & 7) << 4);
            short8 af[4], bfr[4];
#pragma unroll
            for (int mi = 0; mi < 4; ++mi) {
                const int r = wr * 64 + mi * 16 + lo;
                af[mi] = *(const short8*)&As[buf][r * 64 + (kb >> 1)];
            }
#pragma unroll
            for (int ni = 0; ni < 4; ++ni) {
                const int r = wc * 64 + ni * 16 + lo;
                bfr[ni] = *(const short8*)&Bs[buf][r * 64 + (kb >> 1)];
            }
#pragma unroll
            for (int mi = 0; mi < 4; ++mi)
#pragma unroll
                for (int ni = 0; ni < 4; ++ni)
                    acc[mi][ni] = __builtin_amdgcn_mfma_f32_16x16x32_bf16(
                        af[mi], bfr[ni], acc[mi][ni], 0, 0, 0);
        }
        asm volatile("s_waitcnt vmcnt(0)");
        __syncthreads();
    }

    // epilogue
    float bv[4];
#pragma unroll
    for (int ni = 0; ni < 4; ++ni) bv[ni] = bias[n0 + wc * 64 + ni * 16 + lo];
#pragma unroll
    for (int mi = 0; mi < 4; ++mi) {
#pragma unroll
        for (int i = 0; i < 4; ++i) {
            const int row = m0 + wr * 64 + mi * 16 + g * 4 + i;
            if (row < M) {
#pragma unroll
                for (int ni = 0; ni < 4; ++ni) {
                    const int col = n0 + wc * 64 + ni * 16 + lo;
                    float v = acc[mi][ni][i] + bv[ni];
                    if (GELU) v = 0.5f * v * (1.0f + erff(v * 0.70710678118654752f));
                    if (RES)  v += res[(size_t)row * N + col];
                    if (OBF) ((ushort*)Cout)[(size_t)row * N + col] = f2bf(v);
                    else     ((float*)Cout)[(size_t)row * N + col] = v;
                }
            }
        }
    }
}

// ---------------- repack K,V (bf16 qkv) -> Kb[bh][832][32], Vt[bh][32][832] ----------------
__global__ __launch_bounds__(256) void k_repack(
    const ushort* __restrict__ qkv, ushort* __restrict__ Kb, ushort* __restrict__ Vt)
{
    const int bh = blockIdx.x, tt = blockIdx.y;
    const int b = bh >> 3, h = bh & 7;
    const int tid = threadIdx.x;
    const int r = tid >> 2, c = tid & 3;
    const int t = tt * 64 + r;
    __shared__ ushort vtile[64][40];
    ushort8 k8 = {0,0,0,0,0,0,0,0}, v8 = {0,0,0,0,0,0,0,0};
    if (t < T) {
        const ushort* kp = qkv + ((size_t)(b * T + t) * 3 + 1) * D + h * HD + c * 8;
        k8 = *(const ushort8*)kp;
        v8 = *(const ushort8*)(kp + D);
    }
    *(ushort8*)(Kb + ((size_t)bh * TPAD + tt * 64 + r) * HD + c * 8) = k8;
    *(ushort8*)&vtile[r][c * 8] = v8;
    __syncthreads();
    const int d = tid >> 3, cc = tid & 7;
    ushort8 o;
#pragma unroll
    for (int j = 0; j < 8; ++j) o[j] = vtile[cc * 8 + j][d];
    *(ushort8*)(Vt + ((size_t)bh * HD + d) * TPAD + tt * 64 + cc * 8) = o;
}

// ---------------- flash attention (bf16 qkv in, bf16 out) ----------------
__global__ __launch_bounds__(256) void k_flash(
    const ushort* __restrict__ qkv, const ushort* __restrict__ Kb,
    const ushort* __restrict__ Vt, const int* __restrict__ len0,
    const int* __restrict__ len1, ushort* __restrict__ out)
{
    const int qt = blockIdx.x;       // 0..12
    const int bh = blockIdx.y;       // 0..127
    const int b = bh >> 3, h = bh & 7;
    const int tid = threadIdx.x, lane = tid & 63, w = tid >> 6;
    const int lo = lane & 15, g = lane >> 4;
    const int q0 = qt * 64 + w * 16;
    const int l0b = len0[b], l1b = len1[b];

    __shared__ ushort Ks[64][40];
    __shared__ ushort Vs[32][72];
    __shared__ ushort Ps[4][16][72];

    int qrow = q0 + lo; if (qrow > T - 1) qrow = T - 1;
    short8 qf = *(const short8*)(qkv + ((size_t)(b * T + qrow) * 3) * D + h * HD + g * 8);

    f32x4 o0 = {0.f, 0.f, 0.f, 0.f}, o1 = {0.f, 0.f, 0.f, 0.f};
    float mrow[4] = {-1e30f, -1e30f, -1e30f, -1e30f};
    float srow[4] = {0.f, 0.f, 0.f, 0.f};

    const int kts = (qt >= 8 && qt < 12) ? 8 : 0;
    const int ntiles = (qt - kts + 1) + (qt < 12 ? 1 : 0);

    for (int it = 0; it < ntiles; ++it) {
        int kt = kts + it; if (kt > qt) kt = 12;
        const int k0 = kt * 64;

        __syncthreads();
        {
            const int r = tid >> 2, c = tid & 3;
            *(ushort8*)&Ks[r][c * 8] =
                *(const ushort8*)(Kb + ((size_t)bh * TPAD + k0 + r) * HD + c * 8);
            const int dd = tid >> 3, cc = tid & 7;
            *(ushort8*)&Vs[dd][cc * 8] =
                *(const ushort8*)(Vt + ((size_t)bh * HD + dd) * TPAD + k0 + cc * 8);
        }
        __syncthreads();

        f32x4 s[4];
#pragma unroll
        for (int n = 0; n < 4; ++n) {
            short8 kf = *(const short8*)&Ks[n * 16 + lo][g * 8];
            f32x4 z = {0.f, 0.f, 0.f, 0.f};
            s[n] = __builtin_amdgcn_mfma_f32_16x16x32_bf16(qf, kf, z, 0, 0, 0);
        }

        float p[4][4];
        float tm[4] = {-1e30f, -1e30f, -1e30f, -1e30f};
#pragma unroll
        for (int n = 0; n < 4; ++n) {
            const int k = k0 + n * 16 + lo;
            const bool kval = (k < L0) ? (k < l0b) : (k < NS_S) ? ((k - L0) < l1b) : true;
#pragma unroll
            for (int i = 0; i < 4; ++i) {
                const int q = q0 + g * 4 + i;
                bool m = (q < L0)   ? ((k <= q) || (k >= NS_S && k < NS_E))
                       : (q < NS_S) ? ((k >= L0 && k <= q) || (k >= NS_S && k < NS_E))
                       : (q < NS_E) ? (k < NS_E)
                                    : ((k < NS_E) || (k == T - 1));
                const float sv = (m && kval) ? s[n][i] * SCALE : -1e30f;
                p[n][i] = sv;
                tm[i] = fmaxf(tm[i], sv);
            }
        }
#pragma unroll
        for (int i = 0; i < 4; ++i) {
            float t0 = tm[i];
            t0 = fmaxf(t0, __shfl_xor(t0, 1));
            t0 = fmaxf(t0, __shfl_xor(t0, 2));
            t0 = fmaxf(t0, __shfl_xor(t0, 4));
            t0 = fmaxf(t0, __shfl_xor(t0, 8));
            const float mnew = fmaxf(mrow[i], t0);
            const float scl = __expf(mrow[i] - mnew);
            mrow[i] = mnew;
            srow[i] *= scl;
            o0[i] *= scl; o1[i] *= scl;
            float rs = 0.f;
#pragma unroll
            for (int n = 0; n < 4; ++n) {
                const float e = (p[n][i] > -1e29f) ? __expf(p[n][i] - mnew) : 0.f;
                p[n][i] = e;
                rs += e;
            }
            srow[i] += rs;
        }

#pragma unroll
        for (int n = 0; n < 4; ++n)
#pragma unroll
            for (int i = 0; i < 4; ++i)
                Ps[w][g * 4 + i][n * 16 + lo] = f2bf(p[n][i]);
        __syncthreads();
#pragma unroll
        for (int kk = 0; kk < 2; ++kk) {
            short8 pf = *(const short8*)&Ps[w][lo][kk * 32 + g * 8];
            short8 v0 = *(const short8*)&Vs[lo][kk * 32 + g * 8];
            short8 v1 = *(const short8*)&Vs[16 + lo][kk * 32 + g * 8];
            o0 = __builtin_amdgcn_mfma_f32_16x16x32_bf16(pf, v0, o0, 0, 0, 0);
            o1 = __builtin_amdgcn_mfma_f32_16x16x32_bf16(pf, v1, o1, 0, 0, 0);
        }
    }

#pragma unroll
    for (int i = 0; i < 4; ++i) {
        float ssum = srow[i];
        ssum += __shfl_xor(ssum, 1);
        ssum += __shfl_xor(ssum, 2);
        ssum += __shfl_xor(ssum, 4);
        ssum += __shfl_xor(ssum, 8);
        const float inv = 1.f / fmaxf(ssum, 1e-30f);
        const int q = q0 + g * 4 + i;
        if (q < T) {
            ushort* orow = out + (size_t)(b * T + q) * D + h * HD;
            orow[lo]      = f2bf(o0[i] * inv);
            orow[16 + lo] = f2bf(o1[i] * inv);
        }
    }
}

extern "C" void kernel_launch(void* const* d_in, const int* in_sizes, int n_in,
                              void* d_out, int out_size, void* d_ws, size_t ws_size,
                              hipStream_t stream)
{
    const float* seq0 = (const float*)d_in[0];
    const float* seq1 = (const float*)d_in[1];
    const int*   len0 = (const int*)d_in[2];
    const int*   len1 = (const int*)d_in[3];
    const float* nst  = (const float*)d_in[4];
    const float* dom  = (const float*)d_in[5];
    const float* cls  = (const float*)d_in[6];
    const float* ln1w = (const float*)d_in[7];
    const float* ln1b = (const float*)d_in[8];
    const float* qkvw = (const float*)d_in[9];
    const float* qkvb = (const float*)d_in[10];
    const float* outw = (const float*)d_in[11];
    const float* outb = (const float*)d_in[12];
    const float* ln2w = (const float*)d_in[13];
    const float* ln2b = (const float*)d_in[14];
    const float* f1w  = (const float*)d_in[15];
    const float* f1b  = (const float*)d_in[16];
    const float* f2w  = (const float*)d_in[17];
    const float* f2b  = (const float*)d_in[18];
    const float* flnw = (const float*)d_in[19];
    const float* flnb = (const float*)d_in[20];

    float*  x   = (float*)d_ws;                         // NTOK*D f32
    ushort* xn  = (ushort*)(x + (size_t)NTOK * D);      // NTOK*D bf16 (LN out / attn out)
    ushort* big = xn + (size_t)NTOK * D;                // NTOK*4D bf16 (qkv 3D / ffn hidden 4D)
    ushort* Kb  = big + (size_t)NTOK * HM * D;          // 128*832*32
    ushort* Vt  = Kb + (size_t)B * H * TPAD * HD;       // 128*32*832
    ushort* qkvw_t = Vt + (size_t)B * H * TPAD * HD;    // NL*768*256
    ushort* outw_t = qkvw_t + (size_t)NL * 768 * 256;   // NL*256*256
    ushort* f1w_t  = outw_t + (size_t)NL * 256 * 256;   // NL*1024*256
    ushort* f2w_t  = f1w_t  + (size_t)NL * 1024 * 256;  // NL*256*1024

    // one-time weight transpose+convert
    k_wprep<<<dim3(256 / 32, 768 / 32, NL), 256, 0, stream>>>(qkvw, qkvw_t, 256, 768);
    k_wprep<<<dim3(256 / 32, 256 / 32, NL), 256, 0, stream>>>(outw, outw_t, 256, 256);
    k_wprep<<<dim3(256 / 32, 1024 / 32, NL), 256, 0, stream>>>(f1w, f1w_t, 256, 1024);
    k_wprep<<<dim3(1024 / 32, 256 / 32, NL), 256, 0, stream>>>(f2w, f2w_t, 1024, 256);

    k_build_x<<<NTOK, 256, 0, stream>>>(seq0, seq1, nst, dom, cls, x);

    const int lnGrid = (NTOK + 3) / 4;
    const int gmm = (NTOK + 127) / 128;   // 101

    for (int l = 0; l < NL; ++l) {
        k_ln<<<lnGrid, 256, 0, stream>>>(x, ln1w + l * D, ln1b + l * D, xn, NTOK);
        k_gemm_mfma<false, false, true><<<dim3(gmm, 6), 256, 0, stream>>>(
            xn, qkvw_t + (size_t)l * 768 * 256, qkvb + (size_t)l * 3 * D, big, nullptr,
            NTOK, 3 * D, D);
        k_repack<<<dim3(B * H, TPAD / 64), 256, 0, stream>>>(big, Kb, Vt);
        k_flash<<<dim3(TPAD / 64, B * H), 256, 0, stream>>>(big, Kb, Vt, len0, len1, xn);
        k_gemm_mfma<false, true, false><<<dim3(gmm, 2), 256, 0, stream>>>(
            xn, outw_t + (size_t)l * 256 * 256, outb + (size_t)l * D, x, x,
            NTOK, D, D);
        k_ln<<<lnGrid, 256, 0, stream>>>(x, ln2w + l * D, ln2b + l * D, xn, NTOK);
        k_gemm_mfma<true, false, true><<<dim3(gmm, 8), 256, 0, stream>>>(
            xn, f1w_t + (size_t)l * 1024 * 256, f1b + (size_t)l * HM * D, big, nullptr,
            NTOK, HM * D, D);
        k_gemm_mfma<false, true, false><<<dim3(gmm, 2), 256, 0, stream>>>(
            big, f2w_t + (size_t)l * 256 * 1024, f2b + (size_t)l * D, x, x,
            NTOK, D, HM * D);
    }
    k_final_ln<<<B, 64, 0, stream>>>(x, flnw, flnb, (float*)d_out);
}

// Round 4
// 638.088 us; speedup vs baseline: 7.2440x; 1.0456x over previous
//
#include <hip/hip_runtime.h>
#include <hip/hip_bf16.h>
#include <math.h>

typedef __attribute__((ext_vector_type(8))) unsigned short ushort8;
typedef __attribute__((ext_vector_type(8))) short short8;
typedef __attribute__((ext_vector_type(4))) float f32x4;
typedef __attribute__((ext_vector_type(4))) unsigned short ushort4v;
typedef __attribute__((ext_vector_type(4))) int i32x4;
typedef unsigned int u32;

namespace {
constexpr int B = 16, L0 = 512, L1 = 256, NS = 32, D = 256, H = 8, NL = 4, HM = 4;
constexpr int T = L0 + L1 + NS + 1;   // 801
constexpr int HD = D / H;             // 32
constexpr int NTOK = B * T;           // 12816
constexpr int NS_S = L0 + L1;         // 768
constexpr int NS_E = NS_S + NS;       // 800
constexpr int TPAD = 832;             // 13*64
constexpr float EPS = 1e-5f;
constexpr float SCALE = 0.17677669529663687f;  // 32^-0.5
}

__device__ __forceinline__ ushort f2bf(float f) {
    union { float f; unsigned u; } v; v.f = f;
    return (ushort)((v.u + 0x7fffu + ((v.u >> 16) & 1u)) >> 16);
}

__device__ __forceinline__ u32 cvtpk(float a, float b) {
    u32 r;
    asm("v_cvt_pk_bf16_f32 %0, %1, %2" : "=v"(r) : "v"(a), "v"(b));
    return r;
}

__device__ __forceinline__ void gload_lds16(const void* g, void* l) {
    __builtin_amdgcn_global_load_lds(
        (const __attribute__((address_space(1))) u32*)g,
        (__attribute__((address_space(3))) u32*)l, 16, 0, 0);
}

// ---------------- build x ----------------
__global__ __launch_bounds__(256) void k_build_x(
    const float* __restrict__ s0, const float* __restrict__ s1,
    const float* __restrict__ ns, const float* __restrict__ dom,
    const float* __restrict__ cls, float* __restrict__ x)
{
    const int row = blockIdx.x;
    const int b = row / T, t = row % T;
    const int d = threadIdx.x;
    float v;
    if (t < L0)        v = s0[((size_t)b * L0 + t) * D + d] + dom[d];
    else if (t < NS_S) v = s1[((size_t)b * L1 + (t - L0)) * D + d] + dom[D + d];
    else if (t < NS_E) v = ns[((size_t)b * NS + (t - NS_S)) * D + d];
    else               v = cls[d];
    x[(size_t)row * D + d] = v;
}

// ---------------- weight prep: W[K][N] f32 -> W^T[N][K] bf16 ----------------
__global__ __launch_bounds__(256) void k_wprep(
    const float* __restrict__ src, ushort* __restrict__ dst, int K, int N)
{
    const size_t off = (size_t)blockIdx.z * K * N;
    src += off; dst += off;
    __shared__ float t[32][33];
    const int kb = blockIdx.x * 32, nb = blockIdx.y * 32;
    const int c = threadIdx.x & 31, r8 = threadIdx.x >> 5;
#pragma unroll
    for (int rr = 0; rr < 32; rr += 8)
        t[r8 + rr][c] = src[(size_t)(kb + r8 + rr) * N + nb + c];
    __syncthreads();
#pragma unroll
    for (int rr = 0; rr < 32; rr += 8)
        dst[(size_t)(nb + r8 + rr) * K + kb + c] = f2bf(t[c][r8 + rr]);
}

// ---------------- LayerNorm: fp32 in -> bf16 out ----------------
__global__ __launch_bounds__(256) void k_ln(
    const float* __restrict__ x, const float* __restrict__ w,
    const float* __restrict__ bsh, ushort* __restrict__ y, int nrows)
{
    const int wid = threadIdx.x >> 6, lane = threadIdx.x & 63;
    const int row = blockIdx.x * 4 + wid;
    if (row >= nrows) return;
    float4 v = *(const float4*)(x + (size_t)row * D + lane * 4);
    float s  = v.x + v.y + v.z + v.w;
    float ss = v.x * v.x + v.y * v.y + v.z * v.z + v.w * v.w;
#pragma unroll
    for (int o = 32; o; o >>= 1) { s += __shfl_xor(s, o); ss += __shfl_xor(ss, o); }
    const float mean = s * (1.f / D);
    const float var  = ss * (1.f / D) - mean * mean;
    const float r = rsqrtf(var + EPS);
    float4 wv = *(const float4*)(w + lane * 4);
    float4 bv = *(const float4*)(bsh + lane * 4);
    ushort4v o4;
    o4[0] = f2bf((v.x - mean) * r * wv.x + bv.x);
    o4[1] = f2bf((v.y - mean) * r * wv.y + bv.y);
    o4[2] = f2bf((v.z - mean) * r * wv.z + bv.z);
    o4[3] = f2bf((v.w - mean) * r * wv.w + bv.w);
    *(ushort4v*)(y + (size_t)row * D + lane * 4) = o4;
}

// ---------------- final LN on CLS row (fp32 out) ----------------
__global__ __launch_bounds__(64) void k_final_ln(
    const float* __restrict__ x, const float* __restrict__ w,
    const float* __restrict__ bsh, float* __restrict__ out)
{
    const int b = blockIdx.x, lane = threadIdx.x;
    const float* xr = x + (size_t)(b * T + (T - 1)) * D;
    float4 v = *(const float4*)(xr + lane * 4);
    float s  = v.x + v.y + v.z + v.w;
    float ss = v.x * v.x + v.y * v.y + v.z * v.z + v.w * v.w;
#pragma unroll
    for (int o = 32; o; o >>= 1) { s += __shfl_xor(s, o); ss += __shfl_xor(ss, o); }
    const float mean = s * (1.f / D);
    const float var  = ss * (1.f / D) - mean * mean;
    const float r = rsqrtf(var + EPS);
    float4 wv = *(const float4*)(w + lane * 4);
    float4 bv = *(const float4*)(bsh + lane * 4);
    float4 o4;
    o4.x = (v.x - mean) * r * wv.x + bv.x;
    o4.y = (v.y - mean) * r * wv.y + bv.y;
    o4.z = (v.z - mean) * r * wv.z + bv.z;
    o4.w = (v.w - mean) * r * wv.w + bv.w;
    *(float4*)(out + (size_t)b * D + lane * 4) = o4;
}

// ---------------- bf16 MFMA GEMM (unchanged from r3) ----------------
template<bool GELU, bool RES, bool OBF>
__global__ __launch_bounds__(256) void k_gemm_mfma(
    const ushort* __restrict__ A, const ushort* __restrict__ Wt,
    const float* __restrict__ bias, void* __restrict__ Cout,
    const float* __restrict__ res, int M, int N, int K)
{
    __shared__ ushort As[2][128 * 64];
    __shared__ ushort Bs[2][128 * 64];
    const int tid = threadIdx.x;
    const int lane = tid & 63, w = tid >> 6;
    const int lo = lane & 15, g = lane >> 4;
    const int wr = w >> 1, wc = w & 1;
    const int m0 = blockIdx.x * 128, n0 = blockIdx.y * 128;

    f32x4 zero = {0.f, 0.f, 0.f, 0.f};
    f32x4 acc[4][4];
#pragma unroll
    for (int mi = 0; mi < 4; ++mi)
#pragma unroll
        for (int ni = 0; ni < 4; ++ni) acc[mi][ni] = zero;

    const ushort* srcA[4];
    const ushort* srcB[4];
    int ldsOff[4];
#pragma unroll
    for (int i = 0; i < 4; ++i) {
        const int idx16 = (w * 4 + i) * 64 + lane;
        const int row = idx16 >> 3;
        const int scb = ((idx16 & 7) * 16) ^ ((row & 7) << 4);
        int arow = m0 + row; if (arow >= M) arow = M - 1;
        srcA[i] = A  + (size_t)arow * K + (scb >> 1);
        srcB[i] = Wt + (size_t)(n0 + row) * K + (scb >> 1);
        ldsOff[i] = (w * 4 + i) * 512;
    }

    const int NT = K >> 6;

#pragma unroll
    for (int i = 0; i < 4; ++i) {
        gload_lds16(srcA[i], &As[0][ldsOff[i]]);
        gload_lds16(srcB[i], &Bs[0][ldsOff[i]]);
    }
    asm volatile("s_waitcnt vmcnt(0)");
    __syncthreads();

    for (int t = 0; t < NT; ++t) {
        const int buf = t & 1;
        if (t + 1 < NT) {
            const int nb = buf ^ 1, ko = (t + 1) * 64;
#pragma unroll
            for (int i = 0; i < 4; ++i) {
                gload_lds16(srcA[i] + ko, &As[nb][ldsOff[i]]);
                gload_lds16(srcB[i] + ko, &Bs[nb][ldsOff[i]]);
            }
        }
#pragma unroll
        for (int kk = 0; kk < 2; ++kk) {
            const int kb = (kk * 64 + g * 16) ^ ((lo & 7) << 4);
            short8 af[4], bfr[4];
#pragma unroll
            for (int mi = 0; mi < 4; ++mi) {
                const int r = wr * 64 + mi * 16 + lo;
                af[mi] = *(const short8*)&As[buf][r * 64 + (kb >> 1)];
            }
#pragma unroll
            for (int ni = 0; ni < 4; ++ni) {
                const int r = wc * 64 + ni * 16 + lo;
                bfr[ni] = *(const short8*)&Bs[buf][r * 64 + (kb >> 1)];
            }
#pragma unroll
            for (int mi = 0; mi < 4; ++mi)
#pragma unroll
                for (int ni = 0; ni < 4; ++ni)
                    acc[mi][ni] = __builtin_amdgcn_mfma_f32_16x16x32_bf16(
                        af[mi], bfr[ni], acc[mi][ni], 0, 0, 0);
        }
        asm volatile("s_waitcnt vmcnt(0)");
        __syncthreads();
    }

    float bv[4];
#pragma unroll
    for (int ni = 0; ni < 4; ++ni) bv[ni] = bias[n0 + wc * 64 + ni * 16 + lo];
#pragma unroll
    for (int mi = 0; mi < 4; ++mi) {
#pragma unroll
        for (int i = 0; i < 4; ++i) {
            const int row = m0 + wr * 64 + mi * 16 + g * 4 + i;
            if (row < M) {
#pragma unroll
                for (int ni = 0; ni < 4; ++ni) {
                    const int col = n0 + wc * 64 + ni * 16 + lo;
                    float v = acc[mi][ni][i] + bv[ni];
                    if (GELU) v = 0.5f * v * (1.0f + erff(v * 0.70710678118654752f));
                    if (RES)  v += res[(size_t)row * N + col];
                    if (OBF) ((ushort*)Cout)[(size_t)row * N + col] = f2bf(v);
                    else     ((float*)Cout)[(size_t)row * N + col] = v;
                }
            }
        }
    }
}

// ---------------- repack K,V (bf16 qkv) -> Kb[bh][832][32], Vt[bh][32][832] ----------------
__global__ __launch_bounds__(256) void k_repack(
    const ushort* __restrict__ qkv, ushort* __restrict__ Kb, ushort* __restrict__ Vt)
{
    const int bh = blockIdx.x, tt = blockIdx.y;
    const int b = bh >> 3, h = bh & 7;
    const int tid = threadIdx.x;
    const int r = tid >> 2, c = tid & 3;
    const int t = tt * 64 + r;
    __shared__ ushort vtile[64][40];
    ushort8 k8 = {0,0,0,0,0,0,0,0}, v8 = {0,0,0,0,0,0,0,0};
    if (t < T) {
        const ushort* kp = qkv + ((size_t)(b * T + t) * 3 + 1) * D + h * HD + c * 8;
        k8 = *(const ushort8*)kp;
        v8 = *(const ushort8*)(kp + D);
    }
    *(ushort8*)(Kb + ((size_t)bh * TPAD + tt * 64 + r) * HD + c * 8) = k8;
    *(ushort8*)&vtile[r][c * 8] = v8;
    __syncthreads();
    const int d = tid >> 3, cc = tid & 7;
    ushort8 o;
#pragma unroll
    for (int j = 0; j < 8; ++j) o[j] = vtile[cc * 8 + j][d];
    *(ushort8*)(Vt + ((size_t)bh * HD + d) * TPAD + tt * 64 + cc * 8) = o;
}

// ---------------- flash attention v2: swapped QK^T, in-register softmax+exchange ----------------
__global__ __launch_bounds__(256) void k_flash(
    const ushort* __restrict__ qkv, const ushort* __restrict__ Kb,
    const ushort* __restrict__ Vt, const int* __restrict__ len0,
    const int* __restrict__ len1, ushort* __restrict__ out)
{
    const int bh = blockIdx.x;       // x = bh -> all 13 q-tiles of one bh on one XCD
    const int qt = blockIdx.y;       // 0..12
    const int b = bh >> 3, h = bh & 7;
    const int tid = threadIdx.x, lane = tid & 63, w = tid >> 6;
    const int lo = lane & 15, g = lane >> 4;
    const int b4 = g & 1, b5 = g >> 1;
    const int q = qt * 64 + w * 16 + lo;     // this lane's q-row (column of S^T)
    const int l0b = len0[b], l1b = len1[b];
    const bool qB = q < NS_S, qC = q < NS_E, qA = q < L0;

    __shared__ ushort Ks[2][64][40];   // K rows, stride 80B (16B-aligned)
    __shared__ ushort Vs[2][32][72];   // V^T rows, stride 144B

    // Q B-frag: lane holds Q[q][g*8..g*8+7]
    int qrow = q; if (qrow > T - 1) qrow = T - 1;
    short8 qf = *(const short8*)(qkv + ((size_t)(b * T + qrow) * 3) * D + h * HD + g * 8);

    // staging coords (256 threads, 16B each)
    const int kr = tid >> 2, kc = (tid & 3) * 8;
    const int vr = tid >> 3, vc = (tid & 7) * 8;
    const ushort* Ksrc = Kb + (size_t)bh * TPAD * HD + kr * HD + kc;
    const ushort* Vsrc = Vt + ((size_t)bh * HD + vr) * TPAD + vc;

    f32x4 acc0 = {0.f, 0.f, 0.f, 0.f}, acc1 = {0.f, 0.f, 0.f, 0.f};  // O^T[d][q]
    float mrow = -1e30f, srow = 0.f;

    const int kts = (qt >= 8 && qt < 12) ? 8 : 0;
    const int ntiles = (qt < 12) ? (qt - kts + 2) : 13;
    auto ktile = [&](int it) { int kt = kts + it; return kt > qt ? 12 : kt; };

    // prologue: stage tile 0
    int k0 = ktile(0) * 64;
    ushort8 kreg = *(const ushort8*)(Ksrc + (size_t)k0 * HD);
    ushort8 vreg = *(const ushort8*)(Vsrc + k0);
    *(ushort8*)&Ks[0][kr][kc] = kreg;
    *(ushort8*)&Vs[0][vr][vc] = vreg;

    for (int it = 0; it < ntiles; ++it) {
        const int cur = it & 1;
        k0 = ktile(it) * 64;
        __syncthreads();
        if (it + 1 < ntiles) {                       // prefetch next tile into regs
            const int k1 = ktile(it + 1) * 64;
            kreg = *(const ushort8*)(Ksrc + (size_t)k1 * HD);
            vreg = *(const ushort8*)(Vsrc + k1);
        }

        // S^T tile: 4 MFMAs; lane holds S[q][k0 + n*16 + g*4 + i]
        float pv[4][4];
        float tmax = -1e30f;
#pragma unroll
        for (int n = 0; n < 4; ++n) {
            short8 kf = *(const short8*)&Ks[cur][n * 16 + lo][g * 8];
            f32x4 z = {0.f, 0.f, 0.f, 0.f};
            f32x4 sn = __builtin_amdgcn_mfma_f32_16x16x32_bf16(kf, qf, z, 0, 0, 0);
#pragma unroll
            for (int i = 0; i < 4; ++i) {
                const int k = k0 + n * 16 + g * 4 + i;
                const bool kval = (k < L0) ? (k < l0b) : ((k >= NS_S) || (k - L0 < l1b));
                const bool ns = (k >= NS_S) && (k < NS_E);
                const bool m = qB ? ((k <= q && (qA || k >= L0)) || ns)
                             : qC ? (k < NS_E)
                                  : ((k < NS_E) || (k == q));
                const float sv = (m && kval) ? sn[i] * SCALE : -1e30f;
                pv[n][i] = sv;
                tmax = fmaxf(tmax, sv);
            }
        }
        tmax = fmaxf(tmax, __shfl_xor(tmax, 16));
        tmax = fmaxf(tmax, __shfl_xor(tmax, 32));
        const float mnew = fmaxf(mrow, tmax);
        const float scl = __expf(mrow - mnew);
        mrow = mnew;

        // exp + pack to bf16 pairs
        u32 C0[4], C1[4];
        float psum = 0.f;
#pragma unroll
        for (int n = 0; n < 4; ++n) {
            float e0 = (pv[n][0] > -1e29f) ? __expf(pv[n][0] - mnew) : 0.f;
            float e1 = (pv[n][1] > -1e29f) ? __expf(pv[n][1] - mnew) : 0.f;
            float e2 = (pv[n][2] > -1e29f) ? __expf(pv[n][2] - mnew) : 0.f;
            float e3 = (pv[n][3] > -1e29f) ? __expf(pv[n][3] - mnew) : 0.f;
            psum += (e0 + e1) + (e2 + e3);
            C0[n] = cvtpk(e0, e1);
            C1[n] = cvtpk(e2, e3);
        }
        psum += __shfl_xor(psum, 16);
        psum += __shfl_xor(psum, 32);
        srow = srow * scl + psum;
#pragma unroll
        for (int i = 0; i < 4; ++i) { acc0[i] *= scl; acc1[i] *= scl; }

        // in-register transpose of P^T into PV B-frags (lane map derived in header analysis)
        u32 pb0u[4], pb1u[4];
#pragma unroll
        for (int n = 0; n < 4; ++n) {
            const u32 F0 = (u32)__shfl_xor((int)C0[n], 16);
            const u32 F1 = (u32)__shfl_xor((int)C1[n], 16);
            const u32 G00 = b4 ? F0 : C0[n];     // C0 of lane (b5, 0)
            const u32 G01 = b4 ? C0[n] : F0;     // C0 of lane (b5, 1)
            const u32 G10 = b4 ? F1 : C1[n];
            const u32 G11 = b4 ? C1[n] : F1;
            const u32 H00 = (u32)__shfl_xor((int)G00, 32);
            const u32 H01 = (u32)__shfl_xor((int)G01, 32);
            const u32 H10 = (u32)__shfl_xor((int)G10, 32);
            const u32 H11 = (u32)__shfl_xor((int)G11, 32);
            const bool keep = (b5 == b4);
            const u32 S00 = keep ? G00 : H00;    // C0 of (b5'=b4, 0)
            const u32 S01 = keep ? G01 : H01;    // C0 of (b5'=b4, 1)
            const u32 S10 = keep ? G10 : H10;
            const u32 S11 = keep ? G11 : H11;
            const bool take = (b5 == (n & 1));   // this n feeds khalf = n>>1 iff b5 == n&1
            if ((n >> 1) == 0) {
                pb0u[0] = take ? S00 : pb0u[0];
                pb0u[1] = take ? S10 : pb0u[1];
                pb0u[2] = take ? S01 : pb0u[2];
                pb0u[3] = take ? S11 : pb0u[3];
            } else {
                pb1u[0] = take ? S00 : pb1u[0];
                pb1u[1] = take ? S10 : pb1u[1];
                pb1u[2] = take ? S01 : pb1u[2];
                pb1u[3] = take ? S11 : pb1u[3];
            }
        }
        i32x4 t0 = { (int)pb0u[0], (int)pb0u[1], (int)pb0u[2], (int)pb0u[3] };
        i32x4 t1 = { (int)pb1u[0], (int)pb1u[1], (int)pb1u[2], (int)pb1u[3] };
        const short8 pb0 = __builtin_bit_cast(short8, t0);
        const short8 pb1 = __builtin_bit_cast(short8, t1);

        // PV: O^T += V^T . P^T
        {
            short8 a00 = *(const short8*)&Vs[cur][lo][g * 8];
            short8 a01 = *(const short8*)&Vs[cur][lo][32 + g * 8];
            short8 a10 = *(const short8*)&Vs[cur][16 + lo][g * 8];
            short8 a11 = *(const short8*)&Vs[cur][16 + lo][32 + g * 8];
            acc0 = __builtin_amdgcn_mfma_f32_16x16x32_bf16(a00, pb0, acc0, 0, 0, 0);
            acc0 = __builtin_amdgcn_mfma_f32_16x16x32_bf16(a01, pb1, acc0, 0, 0, 0);
            acc1 = __builtin_amdgcn_mfma_f32_16x16x32_bf16(a10, pb0, acc1, 0, 0, 0);
            acc1 = __builtin_amdgcn_mfma_f32_16x16x32_bf16(a11, pb1, acc1, 0, 0, 0);
        }

        if (it + 1 < ntiles) {                    // write prefetched tile
            *(ushort8*)&Ks[cur ^ 1][kr][kc] = kreg;
            *(ushort8*)&Vs[cur ^ 1][vr][vc] = vreg;
        }
    }

    // store: lane owns q, d = {g*4+i, 16+g*4+i}
    if (q < T) {
        const float inv = 1.f / fmaxf(srow, 1e-30f);
        ushort* orow = out + (size_t)(b * T + q) * D + h * HD;
        *(u32*)(orow + g * 4)          = cvtpk(acc0[0] * inv, acc0[1] * inv);
        *(u32*)(orow + g * 4 + 2)      = cvtpk(acc0[2] * inv, acc0[3] * inv);
        *(u32*)(orow + 16 + g * 4)     = cvtpk(acc1[0] * inv, acc1[1] * inv);
        *(u32*)(orow + 16 + g * 4 + 2) = cvtpk(acc1[2] * inv, acc1[3] * inv);
    }
}

extern "C" void kernel_launch(void* const* d_in, const int* in_sizes, int n_in,
                              void* d_out, int out_size, void* d_ws, size_t ws_size,
                              hipStream_t stream)
{
    const float* seq0 = (const float*)d_in[0];
    const float* seq1 = (const float*)d_in[1];
    const int*   len0 = (const int*)d_in[2];
    const int*   len1 = (const int*)d_in[3];
    const float* nst  = (const float*)d_in[4];
    const float* dom  = (const float*)d_in[5];
    const float* cls  = (const float*)d_in[6];
    const float* ln1w = (const float*)d_in[7];
    const float* ln1b = (const float*)d_in[8];
    const float* qkvw = (const float*)d_in[9];
    const float* qkvb = (const float*)d_in[10];
    const float* outw = (const float*)d_in[11];
    const float* outb = (const float*)d_in[12];
    const float* ln2w = (const float*)d_in[13];
    const float* ln2b = (const float*)d_in[14];
    const float* f1w  = (const float*)d_in[15];
    const float* f1b  = (const float*)d_in[16];
    const float* f2w  = (const float*)d_in[17];
    const float* f2b  = (const float*)d_in[18];
    const float* flnw = (const float*)d_in[19];
    const float* flnb = (const float*)d_in[20];

    float*  x   = (float*)d_ws;                         // NTOK*D f32
    ushort* xn  = (ushort*)(x + (size_t)NTOK * D);      // NTOK*D bf16
    ushort* big = xn + (size_t)NTOK * D;                // NTOK*4D bf16
    ushort* Kb  = big + (size_t)NTOK * HM * D;          // 128*832*32
    ushort* Vt  = Kb + (size_t)B * H * TPAD * HD;       // 128*32*832
    ushort* qkvw_t = Vt + (size_t)B * H * TPAD * HD;    // NL*768*256
    ushort* outw_t = qkvw_t + (size_t)NL * 768 * 256;   // NL*256*256
    ushort* f1w_t  = outw_t + (size_t)NL * 256 * 256;   // NL*1024*256
    ushort* f2w_t  = f1w_t  + (size_t)NL * 1024 * 256;  // NL*256*1024

    k_wprep<<<dim3(256 / 32, 768 / 32, NL), 256, 0, stream>>>(qkvw, qkvw_t, 256, 768);
    k_wprep<<<dim3(256 / 32, 256 / 32, NL), 256, 0, stream>>>(outw, outw_t, 256, 256);
    k_wprep<<<dim3(256 / 32, 1024 / 32, NL), 256, 0, stream>>>(f1w, f1w_t, 256, 1024);
    k_wprep<<<dim3(1024 / 32, 256 / 32, NL), 256, 0, stream>>>(f2w, f2w_t, 1024, 256);

    k_build_x<<<NTOK, 256, 0, stream>>>(seq0, seq1, nst, dom, cls, x);

    const int lnGrid = (NTOK + 3) / 4;
    const int gmm = (NTOK + 127) / 128;

    for (int l = 0; l < NL; ++l) {
        k_ln<<<lnGrid, 256, 0, stream>>>(x, ln1w + l * D, ln1b + l * D, xn, NTOK);
        k_gemm_mfma<false, false, true><<<dim3(gmm, 6), 256, 0, stream>>>(
            xn, qkvw_t + (size_t)l * 768 * 256, qkvb + (size_t)l * 3 * D, big, nullptr,
            NTOK, 3 * D, D);
        k_repack<<<dim3(B * H, TPAD / 64), 256, 0, stream>>>(big, Kb, Vt);
        k_flash<<<dim3(B * H, TPAD / 64), 256, 0, stream>>>(big, Kb, Vt, len0, len1, xn);
        k_gemm_mfma<false, true, false><<<dim3(gmm, 2), 256, 0, stream>>>(
            xn, outw_t + (size_t)l * 256 * 256, outb + (size_t)l * D, x, x,
            NTOK, D, D);
        k_ln<<<lnGrid, 256, 0, stream>>>(x, ln2w + l * D, ln2b + l * D, xn, NTOK);
        k_gemm_mfma<true, false, true><<<dim3(gmm, 8), 256, 0, stream>>>(
            xn, f1w_t + (size_t)l * 1024 * 256, f1b + (size_t)l * HM * D, big, nullptr,
            NTOK, HM * D, D);
        k_gemm_mfma<false, true, false><<<dim3(gmm, 2), 256, 0, stream>>>(
            big, f2w_t + (size_t)l * 256 * 1024, f2b + (size_t)l * D, x, x,
            NTOK, D, HM * D);
    }
    k_final_ln<<<B, 64, 0, stream>>>(x, flnw, flnb, (float*)d_out);
}

// Round 5
// 554.734 us; speedup vs baseline: 8.3325x; 1.1503x over previous
//
#include <hip/hip_runtime.h>
#include <hip/hip_bf16.h>
#include <math.h>

typedef __attribute__((ext_vector_type(8))) unsigned short ushort8;
typedef __attribute__((ext_vector_type(8))) short short8;
typedef __attribute__((ext_vector_type(4))) float f32x4;
typedef __attribute__((ext_vector_type(4))) unsigned short ushort4v;
typedef __attribute__((ext_vector_type(4))) int i32x4;
typedef unsigned int u32;

namespace {
constexpr int B = 16, L0 = 512, L1 = 256, NS = 32, D = 256, H = 8, NL = 4, HM = 4;
constexpr int T = L0 + L1 + NS + 1;   // 801
constexpr int HD = D / H;             // 32
constexpr int NTOK = B * T;           // 12816
constexpr int NS_S = L0 + L1;         // 768
constexpr int NS_E = NS_S + NS;       // 800
constexpr int TPAD = 832;             // 13*64
constexpr float EPS = 1e-5f;
constexpr float SCALE = 0.17677669529663687f;          // 32^-0.5
constexpr float SCL2  = 0.17677669529663687f * 1.4426950408889634f;  // SCALE*log2e
}

__device__ __forceinline__ ushort f2bf(float f) {
    union { float f; unsigned u; } v; v.f = f;
    return (ushort)((v.u + 0x7fffu + ((v.u >> 16) & 1u)) >> 16);
}

__device__ __forceinline__ u32 cvtpk(float a, float b) {
    u32 r;
    asm("v_cvt_pk_bf16_f32 %0, %1, %2" : "=v"(r) : "v"(a), "v"(b));
    return r;
}

__device__ __forceinline__ void gload_lds16(const void* g, void* l) {
    __builtin_amdgcn_global_load_lds(
        (const __attribute__((address_space(1))) u32*)g,
        (__attribute__((address_space(3))) u32*)l, 16, 0, 0);
}

// ---------------- build x ----------------
__global__ __launch_bounds__(256) void k_build_x(
    const float* __restrict__ s0, const float* __restrict__ s1,
    const float* __restrict__ ns, const float* __restrict__ dom,
    const float* __restrict__ cls, float* __restrict__ x)
{
    const int row = blockIdx.x;
    const int b = row / T, t = row % T;
    const int d = threadIdx.x;
    float v;
    if (t < L0)        v = s0[((size_t)b * L0 + t) * D + d] + dom[d];
    else if (t < NS_S) v = s1[((size_t)b * L1 + (t - L0)) * D + d] + dom[D + d];
    else if (t < NS_E) v = ns[((size_t)b * NS + (t - NS_S)) * D + d];
    else               v = cls[d];
    x[(size_t)row * D + d] = v;
}

// ---------------- weight prep: W[K][N] f32 -> W^T[N][K] bf16 ----------------
__global__ __launch_bounds__(256) void k_wprep(
    const float* __restrict__ src, ushort* __restrict__ dst, int K, int N)
{
    const size_t off = (size_t)blockIdx.z * K * N;
    src += off; dst += off;
    __shared__ float t[32][33];
    const int kb = blockIdx.x * 32, nb = blockIdx.y * 32;
    const int c = threadIdx.x & 31, r8 = threadIdx.x >> 5;
#pragma unroll
    for (int rr = 0; rr < 32; rr += 8)
        t[r8 + rr][c] = src[(size_t)(kb + r8 + rr) * N + nb + c];
    __syncthreads();
#pragma unroll
    for (int rr = 0; rr < 32; rr += 8)
        dst[(size_t)(nb + r8 + rr) * K + kb + c] = f2bf(t[c][r8 + rr]);
}

// ---------------- LayerNorm: fp32 in -> bf16 out ----------------
__global__ __launch_bounds__(256) void k_ln(
    const float* __restrict__ x, const float* __restrict__ w,
    const float* __restrict__ bsh, ushort* __restrict__ y, int nrows)
{
    const int wid = threadIdx.x >> 6, lane = threadIdx.x & 63;
    const int row = blockIdx.x * 4 + wid;
    if (row >= nrows) return;
    float4 v = *(const float4*)(x + (size_t)row * D + lane * 4);
    float s  = v.x + v.y + v.z + v.w;
    float ss = v.x * v.x + v.y * v.y + v.z * v.z + v.w * v.w;
#pragma unroll
    for (int o = 32; o; o >>= 1) { s += __shfl_xor(s, o); ss += __shfl_xor(ss, o); }
    const float mean = s * (1.f / D);
    const float var  = ss * (1.f / D) - mean * mean;
    const float r = rsqrtf(var + EPS);
    float4 wv = *(const float4*)(w + lane * 4);
    float4 bv = *(const float4*)(bsh + lane * 4);
    ushort4v o4;
    o4[0] = f2bf((v.x - mean) * r * wv.x + bv.x);
    o4[1] = f2bf((v.y - mean) * r * wv.y + bv.y);
    o4[2] = f2bf((v.z - mean) * r * wv.z + bv.z);
    o4[3] = f2bf((v.w - mean) * r * wv.w + bv.w);
    *(ushort4v*)(y + (size_t)row * D + lane * 4) = o4;
}

// ---------------- final LN on CLS row (fp32 out) ----------------
__global__ __launch_bounds__(64) void k_final_ln(
    const float* __restrict__ x, const float* __restrict__ w,
    const float* __restrict__ bsh, float* __restrict__ out)
{
    const int b = blockIdx.x, lane = threadIdx.x;
    const float* xr = x + (size_t)(b * T + (T - 1)) * D;
    float4 v = *(const float4*)(xr + lane * 4);
    float s  = v.x + v.y + v.z + v.w;
    float ss = v.x * v.x + v.y * v.y + v.z * v.z + v.w * v.w;
#pragma unroll
    for (int o = 32; o; o >>= 1) { s += __shfl_xor(s, o); ss += __shfl_xor(ss, o); }
    const float mean = s * (1.f / D);
    const float var  = ss * (1.f / D) - mean * mean;
    const float r = rsqrtf(var + EPS);
    float4 wv = *(const float4*)(w + lane * 4);
    float4 bv = *(const float4*)(bsh + lane * 4);
    float4 o4;
    o4.x = (v.x - mean) * r * wv.x + bv.x;
    o4.y = (v.y - mean) * r * wv.y + bv.y;
    o4.z = (v.z - mean) * r * wv.z + bv.z;
    o4.w = (v.w - mean) * r * wv.w + bv.w;
    *(float4*)(out + (size_t)b * D + lane * 4) = o4;
}

// ---------------- bf16 MFMA GEMM (unchanged from r3) ----------------
template<bool GELU, bool RES, bool OBF>
__global__ __launch_bounds__(256) void k_gemm_mfma(
    const ushort* __restrict__ A, const ushort* __restrict__ Wt,
    const float* __restrict__ bias, void* __restrict__ Cout,
    const float* __restrict__ res, int M, int N, int K)
{
    __shared__ ushort As[2][128 * 64];
    __shared__ ushort Bs[2][128 * 64];
    const int tid = threadIdx.x;
    const int lane = tid & 63, w = tid >> 6;
    const int lo = lane & 15, g = lane >> 4;
    const int wr = w >> 1, wc = w & 1;
    const int m0 = blockIdx.x * 128, n0 = blockIdx.y * 128;

    f32x4 zero = {0.f, 0.f, 0.f, 0.f};
    f32x4 acc[4][4];
#pragma unroll
    for (int mi = 0; mi < 4; ++mi)
#pragma unroll
        for (int ni = 0; ni < 4; ++ni) acc[mi][ni] = zero;

    const ushort* srcA[4];
    const ushort* srcB[4];
    int ldsOff[4];
#pragma unroll
    for (int i = 0; i < 4; ++i) {
        const int idx16 = (w * 4 + i) * 64 + lane;
        const int row = idx16 >> 3;
        const int scb = ((idx16 & 7) * 16) ^ ((row & 7) << 4);
        int arow = m0 + row; if (arow >= M) arow = M - 1;
        srcA[i] = A  + (size_t)arow * K + (scb >> 1);
        srcB[i] = Wt + (size_t)(n0 + row) * K + (scb >> 1);
        ldsOff[i] = (w * 4 + i) * 512;
    }

    const int NT = K >> 6;

#pragma unroll
    for (int i = 0; i < 4; ++i) {
        gload_lds16(srcA[i], &As[0][ldsOff[i]]);
        gload_lds16(srcB[i], &Bs[0][ldsOff[i]]);
    }
    asm volatile("s_waitcnt vmcnt(0)");
    __syncthreads();

    for (int t = 0; t < NT; ++t) {
        const int buf = t & 1;
        if (t + 1 < NT) {
            const int nb = buf ^ 1, ko = (t + 1) * 64;
#pragma unroll
            for (int i = 0; i < 4; ++i) {
                gload_lds16(srcA[i] + ko, &As[nb][ldsOff[i]]);
                gload_lds16(srcB[i] + ko, &Bs[nb][ldsOff[i]]);
            }
        }
#pragma unroll
        for (int kk = 0; kk < 2; ++kk) {
            const int kb = (kk * 64 + g * 16) ^ ((lo & 7) << 4);
            short8 af[4], bfr[4];
#pragma unroll
            for (int mi = 0; mi < 4; ++mi) {
                const int r = wr * 64 + mi * 16 + lo;
                af[mi] = *(const short8*)&As[buf][r * 64 + (kb >> 1)];
            }
#pragma unroll
            for (int ni = 0; ni < 4; ++ni) {
                const int r = wc * 64 + ni * 16 + lo;
                bfr[ni] = *(const short8*)&Bs[buf][r * 64 + (kb >> 1)];
            }
#pragma unroll
            for (int mi = 0; mi < 4; ++mi)
#pragma unroll
                for (int ni = 0; ni < 4; ++ni)
                    acc[mi][ni] = __builtin_amdgcn_mfma_f32_16x16x32_bf16(
                        af[mi], bfr[ni], acc[mi][ni], 0, 0, 0);
        }
        asm volatile("s_waitcnt vmcnt(0)");
        __syncthreads();
    }

    float bv[4];
#pragma unroll
    for (int ni = 0; ni < 4; ++ni) bv[ni] = bias[n0 + wc * 64 + ni * 16 + lo];
#pragma unroll
    for (int mi = 0; mi < 4; ++mi) {
#pragma unroll
        for (int i = 0; i < 4; ++i) {
            const int row = m0 + wr * 64 + mi * 16 + g * 4 + i;
            if (row < M) {
#pragma unroll
                for (int ni = 0; ni < 4; ++ni) {
                    const int col = n0 + wc * 64 + ni * 16 + lo;
                    float v = acc[mi][ni][i] + bv[ni];
                    if (GELU) v = 0.5f * v * (1.0f + erff(v * 0.70710678118654752f));
                    if (RES)  v += res[(size_t)row * N + col];
                    if (OBF) ((ushort*)Cout)[(size_t)row * N + col] = f2bf(v);
                    else     ((float*)Cout)[(size_t)row * N + col] = v;
                }
            }
        }
    }
}

// ---------------- repack K,V (bf16 qkv) -> Kb[bh][832][32], Vt[bh][32][832] ----------------
__global__ __launch_bounds__(256) void k_repack(
    const ushort* __restrict__ qkv, ushort* __restrict__ Kb, ushort* __restrict__ Vt)
{
    const int bh = blockIdx.x, tt = blockIdx.y;
    const int b = bh >> 3, h = bh & 7;
    const int tid = threadIdx.x;
    const int r = tid >> 2, c = tid & 3;
    const int t = tt * 64 + r;
    __shared__ ushort vtile[64][40];
    ushort8 k8 = {0,0,0,0,0,0,0,0}, v8 = {0,0,0,0,0,0,0,0};
    if (t < T) {
        const ushort* kp = qkv + ((size_t)(b * T + t) * 3 + 1) * D + h * HD + c * 8;
        k8 = *(const ushort8*)kp;
        v8 = *(const ushort8*)(kp + D);
    }
    *(ushort8*)(Kb + ((size_t)bh * TPAD + tt * 64 + r) * HD + c * 8) = k8;
    *(ushort8*)&vtile[r][c * 8] = v8;
    __syncthreads();
    const int d = tid >> 3, cc = tid & 7;
    ushort8 o;
#pragma unroll
    for (int j = 0; j < 8; ++j) o[j] = vtile[cc * 8 + j][d];
    *(ushort8*)(Vt + ((size_t)bh * HD + d) * TPAD + tt * 64 + cc * 8) = o;
}

// ---------------- flash attention v3: no LDS, no barriers, reg-prefetch, LPT ----------------
__global__ __launch_bounds__(256) void k_flash(
    const ushort* __restrict__ qkv, const ushort* __restrict__ Kb,
    const ushort* __restrict__ Vt, const int* __restrict__ len0,
    const int* __restrict__ len1, ushort* __restrict__ out)
{
    const int bh = blockIdx.x;           // x = bh -> all q-tiles of one bh on one XCD
    const int qt = 12 - blockIdx.y;      // LPT: heavy blocks (qt=12) launch first
    const int b = bh >> 3, h = bh & 7;
    const int tid = threadIdx.x, lane = tid & 63, w = tid >> 6;
    const int lo = lane & 15, g = lane >> 4;
    const int b4 = g & 1, b5 = g >> 1;
    const int q = qt * 64 + w * 16 + lo;     // this lane's q-row
    const int l0b = len0[b], lim01 = L0 + len1[b];

    // per-lane causal window [klo, klim]
    int klo = 0, klim;
    if (q < L0)        klim = q;
    else if (q < NS_S) { klo = L0; klim = q; }
    else if (q < NS_E) klim = NS_E - 1;
    else               klim = q;          // cls row q=800: k<=800; padding lanes unstored

    // Q B-frag
    int qrow = q; if (qrow > T - 1) qrow = T - 1;
    short8 qf = *(const short8*)(qkv + ((size_t)(b * T + qrow) * 3) * D + h * HD + g * 8);

    const ushort* Kbase = Kb + (size_t)bh * TPAD * HD;   // row stride HD (64B, contiguous)
    const ushort* Vbase = Vt + (size_t)bh * HD * TPAD;   // row stride TPAD

    f32x4 acc0 = {0.f, 0.f, 0.f, 0.f}, acc1 = {0.f, 0.f, 0.f, 0.f};  // O^T[d][q]
    float mrow = -1e30f, srow = 0.f;

    const int kts = (qt >= 8 && qt < 12) ? 8 : 0;
    const int ntiles = (qt < 12) ? (qt - kts + 2) : 13;
    auto ktile = [&](int it) { int kt = kts + it; return kt > qt ? 12 : kt; };

    // prologue: K frags of tile 0 into regs
    short8 kf[4];
    {
        const int k0 = ktile(0) * 64;
#pragma unroll
        for (int n = 0; n < 4; ++n)
            kf[n] = *(const short8*)(Kbase + (size_t)(k0 + n * 16 + lo) * HD + g * 8);
    }

    for (int it = 0; it < ntiles; ++it) {
        const int k0 = ktile(it) * 64;

        // issue V loads for this tile early (consumed after softmax)
        const ushort* V0 = Vbase + k0;
        short8 a00 = *(const short8*)(V0 + (size_t)lo * TPAD + g * 8);
        short8 a01 = *(const short8*)(V0 + (size_t)lo * TPAD + 32 + g * 8);
        short8 a10 = *(const short8*)(V0 + (size_t)(16 + lo) * TPAD + g * 8);
        short8 a11 = *(const short8*)(V0 + (size_t)(16 + lo) * TPAD + 32 + g * 8);

        // S^T tile: 4 MFMAs; lane holds S[q][k0 + n*16 + g*4 + i]
        float pv[4][4];
        float tmax = -1e30f;
#pragma unroll
        for (int n = 0; n < 4; ++n) {
            f32x4 z = {0.f, 0.f, 0.f, 0.f};
            f32x4 sn = __builtin_amdgcn_mfma_f32_16x16x32_bf16(kf[n], qf, z, 0, 0, 0);
#pragma unroll
            for (int i = 0; i < 4; ++i) {
                const int k = k0 + n * 16 + g * 4 + i;
                const bool inNS = (k >= NS_S) & (k < NS_E);
                const bool kval = (k < l0b) | ((k >= L0) & (k < lim01)) | (k >= NS_S);
                const bool m = ((k >= klo) & (k <= klim) & kval) | inNS;
                const float sv = m ? sn[i] * SCL2 : -1e30f;
                pv[n][i] = sv;
                tmax = fmaxf(tmax, sv);
            }
        }

        // prefetch next tile's K frags (latency hidden under softmax VALU)
        short8 kf2[4];
        if (it + 1 < ntiles) {
            const int k1 = ktile(it + 1) * 64;
#pragma unroll
            for (int n = 0; n < 4; ++n)
                kf2[n] = *(const short8*)(Kbase + (size_t)(k1 + n * 16 + lo) * HD + g * 8);
        }

        tmax = fmaxf(tmax, __shfl_xor(tmax, 16));
        tmax = fmaxf(tmax, __shfl_xor(tmax, 32));
        const float mnew = fmaxf(mrow, tmax);
        const float scl = exp2f(mrow - mnew);
        mrow = mnew;

        // exp2 + pack to bf16 pairs
        u32 C0[4], C1[4];
        float psum = 0.f;
#pragma unroll
        for (int n = 0; n < 4; ++n) {
            float e0 = exp2f(pv[n][0] - mnew);
            float e1 = exp2f(pv[n][1] - mnew);
            float e2 = exp2f(pv[n][2] - mnew);
            float e3 = exp2f(pv[n][3] - mnew);
            psum += (e0 + e1) + (e2 + e3);
            C0[n] = cvtpk(e0, e1);
            C1[n] = cvtpk(e2, e3);
        }
        psum += __shfl_xor(psum, 16);
        psum += __shfl_xor(psum, 32);
        srow = srow * scl + psum;
#pragma unroll
        for (int i = 0; i < 4; ++i) { acc0[i] *= scl; acc1[i] *= scl; }

        // in-register transpose of P^T into PV B-frags
        u32 pb0u[4], pb1u[4];
#pragma unroll
        for (int n = 0; n < 4; ++n) {
            const u32 F0 = (u32)__shfl_xor((int)C0[n], 16);
            const u32 F1 = (u32)__shfl_xor((int)C1[n], 16);
            const u32 G00 = b4 ? F0 : C0[n];
            const u32 G01 = b4 ? C0[n] : F0;
            const u32 G10 = b4 ? F1 : C1[n];
            const u32 G11 = b4 ? C1[n] : F1;
            const u32 H00 = (u32)__shfl_xor((int)G00, 32);
            const u32 H01 = (u32)__shfl_xor((int)G01, 32);
            const u32 H10 = (u32)__shfl_xor((int)G10, 32);
            const u32 H11 = (u32)__shfl_xor((int)G11, 32);
            const bool keep = (b5 == b4);
            const u32 S00 = keep ? G00 : H00;
            const u32 S01 = keep ? G01 : H01;
            const u32 S10 = keep ? G10 : H10;
            const u32 S11 = keep ? G11 : H11;
            const bool take = (b5 == (n & 1));
            if ((n >> 1) == 0) {
                pb0u[0] = take ? S00 : pb0u[0];
                pb0u[1] = take ? S10 : pb0u[1];
                pb0u[2] = take ? S01 : pb0u[2];
                pb0u[3] = take ? S11 : pb0u[3];
            } else {
                pb1u[0] = take ? S00 : pb1u[0];
                pb1u[1] = take ? S10 : pb1u[1];
                pb1u[2] = take ? S01 : pb1u[2];
                pb1u[3] = take ? S11 : pb1u[3];
            }
        }
        i32x4 t0 = { (int)pb0u[0], (int)pb0u[1], (int)pb0u[2], (int)pb0u[3] };
        i32x4 t1 = { (int)pb1u[0], (int)pb1u[1], (int)pb1u[2], (int)pb1u[3] };
        const short8 pb0 = __builtin_bit_cast(short8, t0);
        const short8 pb1 = __builtin_bit_cast(short8, t1);

        // PV: O^T += V^T . P^T
        acc0 = __builtin_amdgcn_mfma_f32_16x16x32_bf16(a00, pb0, acc0, 0, 0, 0);
        acc0 = __builtin_amdgcn_mfma_f32_16x16x32_bf16(a01, pb1, acc0, 0, 0, 0);
        acc1 = __builtin_amdgcn_mfma_f32_16x16x32_bf16(a10, pb0, acc1, 0, 0, 0);
        acc1 = __builtin_amdgcn_mfma_f32_16x16x32_bf16(a11, pb1, acc1, 0, 0, 0);

#pragma unroll
        for (int n = 0; n < 4; ++n) kf[n] = kf2[n];
    }

    // store: lane owns q, d = {g*4+i, 16+g*4+i}
    if (q < T) {
        const float inv = 1.f / fmaxf(srow, 1e-30f);
        ushort* orow = out + (size_t)(b * T + q) * D + h * HD;
        *(u32*)(orow + g * 4)          = cvtpk(acc0[0] * inv, acc0[1] * inv);
        *(u32*)(orow + g * 4 + 2)      = cvtpk(acc0[2] * inv, acc0[3] * inv);
        *(u32*)(orow + 16 + g * 4)     = cvtpk(acc1[0] * inv, acc1[1] * inv);
        *(u32*)(orow + 16 + g * 4 + 2) = cvtpk(acc1[2] * inv, acc1[3] * inv);
    }
}

extern "C" void kernel_launch(void* const* d_in, const int* in_sizes, int n_in,
                              void* d_out, int out_size, void* d_ws, size_t ws_size,
                              hipStream_t stream)
{
    const float* seq0 = (const float*)d_in[0];
    const float* seq1 = (const float*)d_in[1];
    const int*   len0 = (const int*)d_in[2];
    const int*   len1 = (const int*)d_in[3];
    const float* nst  = (const float*)d_in[4];
    const float* dom  = (const float*)d_in[5];
    const float* cls  = (const float*)d_in[6];
    const float* ln1w = (const float*)d_in[7];
    const float* ln1b = (const float*)d_in[8];
    const float* qkvw = (const float*)d_in[9];
    const float* qkvb = (const float*)d_in[10];
    const float* outw = (const float*)d_in[11];
    const float* outb = (const float*)d_in[12];
    const float* ln2w = (const float*)d_in[13];
    const float* ln2b = (const float*)d_in[14];
    const float* f1w  = (const float*)d_in[15];
    const float* f1b  = (const float*)d_in[16];
    const float* f2w  = (const float*)d_in[17];
    const float* f2b  = (const float*)d_in[18];
    const float* flnw = (const float*)d_in[19];
    const float* flnb = (const float*)d_in[20];

    float*  x   = (float*)d_ws;                         // NTOK*D f32
    ushort* xn  = (ushort*)(x + (size_t)NTOK * D);      // NTOK*D bf16
    ushort* big = xn + (size_t)NTOK * D;                // NTOK*4D bf16
    ushort* Kb  = big + (size_t)NTOK * HM * D;          // 128*832*32
    ushort* Vt  = Kb + (size_t)B * H * TPAD * HD;       // 128*32*832
    ushort* qkvw_t = Vt + (size_t)B * H * TPAD * HD;    // NL*768*256
    ushort* outw_t = qkvw_t + (size_t)NL * 768 * 256;   // NL*256*256
    ushort* f1w_t  = outw_t + (size_t)NL * 256 * 256;   // NL*1024*256
    ushort* f2w_t  = f1w_t  + (size_t)NL * 1024 * 256;  // NL*256*1024

    k_wprep<<<dim3(256 / 32, 768 / 32, NL), 256, 0, stream>>>(qkvw, qkvw_t, 256, 768);
    k_wprep<<<dim3(256 / 32, 256 / 32, NL), 256, 0, stream>>>(outw, outw_t, 256, 256);
    k_wprep<<<dim3(256 / 32, 1024 / 32, NL), 256, 0, stream>>>(f1w, f1w_t, 256, 1024);
    k_wprep<<<dim3(1024 / 32, 256 / 32, NL), 256, 0, stream>>>(f2w, f2w_t, 1024, 256);

    k_build_x<<<NTOK, 256, 0, stream>>>(seq0, seq1, nst, dom, cls, x);

    const int lnGrid = (NTOK + 3) / 4;
    const int gmm = (NTOK + 127) / 128;

    for (int l = 0; l < NL; ++l) {
        k_ln<<<lnGrid, 256, 0, stream>>>(x, ln1w + l * D, ln1b + l * D, xn, NTOK);
        k_gemm_mfma<false, false, true><<<dim3(gmm, 6), 256, 0, stream>>>(
            xn, qkvw_t + (size_t)l * 768 * 256, qkvb + (size_t)l * 3 * D, big, nullptr,
            NTOK, 3 * D, D);
        k_repack<<<dim3(B * H, TPAD / 64), 256, 0, stream>>>(big, Kb, Vt);
        k_flash<<<dim3(B * H, TPAD / 64), 256, 0, stream>>>(big, Kb, Vt, len0, len1, xn);
        k_gemm_mfma<false, true, false><<<dim3(gmm, 2), 256, 0, stream>>>(
            xn, outw_t + (size_t)l * 256 * 256, outb + (size_t)l * D, x, x,
            NTOK, D, D);
        k_ln<<<lnGrid, 256, 0, stream>>>(x, ln2w + l * D, ln2b + l * D, xn, NTOK);
        k_gemm_mfma<true, false, true><<<dim3(gmm, 8), 256, 0, stream>>>(
            xn, f1w_t + (size_t)l * 1024 * 256, f1b + (size_t)l * HM * D, big, nullptr,
            NTOK, HM * D, D);
        k_gemm_mfma<false, true, false><<<dim3(gmm, 2), 256, 0, stream>>>(
            big, f2w_t + (size_t)l * 256 * 1024, f2b + (size_t)l * D, x, x,
            NTOK, D, HM * D);
    }
    k_final_ln<<<B, 64, 0, stream>>>(x, flnw, flnb, (float*)d_out);
}